// Round 2
// baseline (330.401 us; speedup 1.0000x reference)
//
#include <hip/hip_runtime.h>

#define DEVI __device__ __forceinline__

using f32x4 = __attribute__((ext_vector_type(4))) float;
using fvec4 = __attribute__((ext_vector_type(4))) float;
using s16x4 = __attribute__((ext_vector_type(4))) short;
using s16x8 = __attribute__((ext_vector_type(8))) short;

DEVI unsigned short f2bf_rn(float f) {
  union { float f; unsigned u; } v; v.f = f;
  unsigned r = v.u + 0x7fffu + ((v.u >> 16) & 1u);
  return (unsigned short)(r >> 16);
}
DEVI float bf2f(unsigned short h) {
  union { unsigned u; float f; } v; v.u = ((unsigned)h) << 16;
  return v.f;
}
DEVI f32x4 mfma16(s16x8 a, s16x8 b, f32x4 c) {
  return __builtin_amdgcn_mfma_f32_16x16x32_bf16(a, b, c, 0, 0, 0);
}

// ---------------- prep: transpose + split weights ----------------
__global__ __launch_bounds__(256) void k_prep_w(
    const float* __restrict__ wq, const float* __restrict__ wk,
    const float* __restrict__ wv, const float* __restrict__ wo,
    unsigned short* __restrict__ WTh, unsigned short* __restrict__ WTl,
    unsigned short* __restrict__ WOT)
{
  __shared__ float tile[64][65];
  const int z = blockIdx.z;
  const float* src = (z == 0) ? wq : (z == 1) ? wk : (z == 2) ? wv : wo;
  const int k0 = blockIdx.x * 64;
  const int n0 = blockIdx.y * 64;
  const int t = threadIdx.x;
#pragma unroll
  for (int j = 0; j < 4; ++j) {
    int r = (t >> 4) + 16 * j;
    int c = (t & 15) * 4;
    fvec4 v = *(const fvec4*)&src[(size_t)(k0 + r) * 1024 + n0 + c];
#pragma unroll
    for (int i = 0; i < 4; ++i) tile[r][c + i] = v[i];
  }
  __syncthreads();
#pragma unroll
  for (int j = 0; j < 4; ++j) {
    int n = (t >> 4) + 16 * j;
    int kc = (t & 15) * 4;
    s16x4 hv, lv;
#pragma unroll
    for (int i = 0; i < 4; ++i) {
      float f = tile[kc + i][n];
      unsigned short hs = f2bf_rn(f);
      hv[i] = (short)hs;
      lv[i] = (short)f2bf_rn(f - bf2f(hs));
    }
    if (z < 3) {
      size_t o = (size_t)(z * 1024 + n0 + n) * 1024 + k0 + kc;
      *(s16x4*)&WTh[o] = hv;
      *(s16x4*)&WTl[o] = lv;
    } else {
      *(s16x4*)&WOT[(size_t)(n0 + n) * 1024 + k0 + kc] = hv;
    }
  }
}

// ---------------- QKV GEMM: q,k 3-pass split -> f32; v 1-pass -> bf16 ------
__global__ __launch_bounds__(256) void k_gemm_qkv(
    const float* __restrict__ X,
    const unsigned short* __restrict__ WTh, const unsigned short* __restrict__ WTl,
    float* __restrict__ QF, float* __restrict__ KF,
    unsigned short* __restrict__ VB)
{
  __shared__ unsigned short AH[128][40], AL[128][40], BH[128][40], BL[128][40];
  const int cb = blockIdx.x;  // 0..23
  const int rb = blockIdx.y;  // 0..63
  const int t = threadIdx.x;
  const int w = t >> 6, l = t & 63;
  const bool tp = (cb < 16);
  f32x4 acc[4][4];
#pragma unroll
  for (int a = 0; a < 4; ++a)
#pragma unroll
    for (int b = 0; b < 4; ++b) acc[a][b] = (f32x4)0.f;

  for (int ks = 0; ks < 32; ++ks) {
    const int k0 = ks * 32;
#pragma unroll
    for (int j = 0; j < 4; ++j) {
      int r = (t >> 3) + 32 * j;
      int c = (t & 7) * 4;
      fvec4 v = *(const fvec4*)&X[(size_t)(rb * 128 + r) * 1024 + k0 + c];
      s16x4 hv, lv;
#pragma unroll
      for (int i = 0; i < 4; ++i) {
        unsigned short hs = f2bf_rn(v[i]);
        hv[i] = (short)hs;
        lv[i] = (short)f2bf_rn(v[i] - bf2f(hs));
      }
      *(s16x4*)&AH[r][c] = hv;
      *(s16x4*)&AL[r][c] = lv;
    }
#pragma unroll
    for (int j = 0; j < 2; ++j) {
      int r = (t >> 2) + 64 * j;
      int c = (t & 3) * 8;
      *(s16x8*)&BH[r][c] = *(const s16x8*)&WTh[(size_t)(cb * 128 + r) * 1024 + k0 + c];
      if (tp)
        *(s16x8*)&BL[r][c] = *(const s16x8*)&WTl[(size_t)(cb * 128 + r) * 1024 + k0 + c];
    }
    __syncthreads();
    const int wm = (w & 1) * 64, wn = (w >> 1) * 64;
    const int lr = l & 15, ko = (l >> 4) * 8;
    s16x8 ah[4], al[4], bh[4], bl[4];
#pragma unroll
    for (int f = 0; f < 4; ++f) {
      ah[f] = *(const s16x8*)&AH[wm + f * 16 + lr][ko];
      bh[f] = *(const s16x8*)&BH[wn + f * 16 + lr][ko];
    }
    if (tp) {
#pragma unroll
      for (int f = 0; f < 4; ++f) {
        al[f] = *(const s16x8*)&AL[wm + f * 16 + lr][ko];
        bl[f] = *(const s16x8*)&BL[wn + f * 16 + lr][ko];
      }
    }
#pragma unroll
    for (int fa = 0; fa < 4; ++fa)
#pragma unroll
      for (int fb = 0; fb < 4; ++fb) {
        acc[fa][fb] = mfma16(ah[fa], bh[fb], acc[fa][fb]);
        if (tp) {
          acc[fa][fb] = mfma16(ah[fa], bl[fb], acc[fa][fb]);
          acc[fa][fb] = mfma16(al[fa], bh[fb], acc[fa][fb]);
        }
      }
    __syncthreads();
  }
  const int wm = (w & 1) * 64, wn = (w >> 1) * 64;
  const int lr = l & 15, lg = l >> 4;
#pragma unroll
  for (int fa = 0; fa < 4; ++fa)
#pragma unroll
    for (int r = 0; r < 4; ++r) {
      int row = rb * 128 + wm + fa * 16 + lg * 4 + r;
#pragma unroll
      for (int fb = 0; fb < 4; ++fb) {
        int col = cb * 128 + wn + fb * 16 + lr;
        float v = acc[fa][fb][r];
        if (cb < 8) {
          QF[(size_t)row * 1024 + col] = v;
        } else if (cb < 16) {
          KF[(size_t)row * 1024 + col - 1024] = v;
        } else {
          VB[(size_t)row * 1024 + col - 2048] = f2bf_rn(v);
        }
      }
    }
}

// ---------------- fused phi_k + kv ----------------
// grid (8 chunks of 512 rows, 32 bh). Per sub-tile of 64 rows:
//   phi_k = exp(K.omega^T - 0.5||k||^2)/16 (3-pass MFMA), transpose to LDS,
//   kvT[80][256] += [v^T; ones; 0] x phi_k^T  (MFMA over n)
__global__ __launch_bounds__(256, 1) void k_phik_kv(
    const float* __restrict__ KF, const unsigned short* __restrict__ VB,
    const float* __restrict__ omega, float* __restrict__ KVP)
{
  __shared__ unsigned short OH[256][72], OL[256][72];
  __shared__ unsigned short KHs[64][72], KLs[64][72];
  __shared__ unsigned short PKT[256][72];
  __shared__ unsigned short AVT[80][72];
  __shared__ float norm_s[64];
  const int nc = blockIdx.x;  // 0..7
  const int bh = blockIdx.y;  // 0..31
  const int b = bh >> 4, h = bh & 15;
  const int t = threadIdx.x, w = t >> 6, l = t & 63;
  const int lr = l & 15, lg = l >> 4, ko8 = lg * 8;

  // stage omega hi/lo once
#pragma unroll
  for (int j = 0; j < 16; ++j) {
    int e = j * 256 + t;
    int m = e >> 4, c = (e & 15) * 4;
    fvec4 v = *(const fvec4*)&omega[m * 64 + c];
    s16x4 hv, lv;
#pragma unroll
    for (int i = 0; i < 4; ++i) {
      unsigned short hs = f2bf_rn(v[i]);
      hv[i] = (short)hs;
      lv[i] = (short)f2bf_rn(v[i] - bf2f(hs));
    }
    *(s16x4*)&OH[m][c] = hv;
    *(s16x4*)&OL[m][c] = lv;
  }
  // init AVT rows 64..79 (ones row for k_sum, zeros)
  for (int e = t; e < 16 * 64; e += 256) {
    int rr = e >> 6, cc = e & 63;
    AVT[64 + rr][cc] = (rr == 0) ? (unsigned short)0x3F80 : (unsigned short)0;
  }

  f32x4 acc2[5][4];
#pragma unroll
  for (int a = 0; a < 5; ++a)
#pragma unroll
    for (int bb = 0; bb < 4; ++bb) acc2[a][bb] = (f32x4)0.f;

  for (int st = 0; st < 8; ++st) {
    const int n0 = nc * 512 + st * 64;
    __syncthreads();  // prev iter's MFMA reads done; also publishes pre-loop staging
    // stage K tile f32 -> hi/lo + row norms
    {
      int r = t >> 2, cq = (t & 3) * 4;
      float ss = 0.f;
#pragma unroll
      for (int j = 0; j < 4; ++j) {
        int c = cq + 16 * j;
        fvec4 v = *(const fvec4*)&KF[(size_t)(b * 4096 + n0 + r) * 1024 + h * 64 + c];
        s16x4 hv, lv;
#pragma unroll
        for (int i = 0; i < 4; ++i) {
          unsigned short hs = f2bf_rn(v[i]);
          hv[i] = (short)hs;
          lv[i] = (short)f2bf_rn(v[i] - bf2f(hs));
          ss += v[i] * v[i];
        }
        *(s16x4*)&KHs[r][c] = hv;
        *(s16x4*)&KLs[r][c] = lv;
      }
      ss += __shfl_xor(ss, 1);
      ss += __shfl_xor(ss, 2);
      if ((t & 3) == 0) norm_s[r] = 0.5f * ss;
    }
    // stage v^T: rows n0..n0+63 -> AVT[d][n]
    {
      int n = t >> 2, dq = (t & 3) * 16;
      s16x8 v0 = *(const s16x8*)&VB[(size_t)(b * 4096 + n0 + n) * 1024 + h * 64 + dq];
      s16x8 v1 = *(const s16x8*)&VB[(size_t)(b * 4096 + n0 + n) * 1024 + h * 64 + dq + 8];
#pragma unroll
      for (int i = 0; i < 8; ++i) {
        AVT[dq + i][n] = (unsigned short)v0[i];
        AVT[dq + 8 + i][n] = (unsigned short)v1[i];
      }
    }
    __syncthreads();
    // proj MFMA 3-pass
    f32x4 acc[4][4];
#pragma unroll
    for (int a = 0; a < 4; ++a)
#pragma unroll
      for (int bb = 0; bb < 4; ++bb) acc[a][bb] = (f32x4)0.f;
#pragma unroll
    for (int ksub = 0; ksub < 2; ++ksub) {
      int ko = ksub * 32 + ko8;
      s16x8 ah[4], al[4], bh[4], bl[4];
#pragma unroll
      for (int f = 0; f < 4; ++f) {
        ah[f] = *(const s16x8*)&KHs[f * 16 + lr][ko];
        al[f] = *(const s16x8*)&KLs[f * 16 + lr][ko];
        bh[f] = *(const s16x8*)&OH[w * 64 + f * 16 + lr][ko];
        bl[f] = *(const s16x8*)&OL[w * 64 + f * 16 + lr][ko];
      }
#pragma unroll
      for (int fa = 0; fa < 4; ++fa)
#pragma unroll
        for (int fb = 0; fb < 4; ++fb) {
          acc[fa][fb] = mfma16(ah[fa], bh[fb], acc[fa][fb]);
          acc[fa][fb] = mfma16(ah[fa], bl[fb], acc[fa][fb]);
          acc[fa][fb] = mfma16(al[fa], bh[fb], acc[fa][fb]);
        }
    }
    // exp -> phi_k, scatter transposed into PKT[m][n]
#pragma unroll
    for (int fa = 0; fa < 4; ++fa)
#pragma unroll
      for (int r = 0; r < 4; ++r) {
        int n = fa * 16 + lg * 4 + r;
        float nm = norm_s[n];
#pragma unroll
        for (int fb = 0; fb < 4; ++fb) {
          int m = w * 64 + fb * 16 + lr;
          float p = __expf(acc[fa][fb][r] - nm) * 0.0625f;
          PKT[m][n] = f2bf_rn(p);
        }
      }
    __syncthreads();
    // kv MFMA: contraction over n (64) in 2 K-steps
#pragma unroll
    for (int ksub = 0; ksub < 2; ++ksub) {
      int ko = ksub * 32 + ko8;
      s16x8 fA[5], fB[4];
#pragma unroll
      for (int f = 0; f < 5; ++f) fA[f] = *(const s16x8*)&AVT[f * 16 + lr][ko];
#pragma unroll
      for (int f = 0; f < 4; ++f) fB[f] = *(const s16x8*)&PKT[w * 64 + f * 16 + lr][ko];
#pragma unroll
      for (int fa = 0; fa < 5; ++fa)
#pragma unroll
        for (int fb = 0; fb < 4; ++fb) acc2[fa][fb] = mfma16(fA[fa], fB[fb], acc2[fa][fb]);
    }
  }
  // write partials
#pragma unroll
  for (int fa = 0; fa < 5; ++fa)
#pragma unroll
    for (int r = 0; r < 4; ++r) {
      int dp = fa * 16 + lg * 4 + r;
#pragma unroll
      for (int fb = 0; fb < 4; ++fb) {
        int m = w * 64 + fb * 16 + lr;
        KVP[(size_t)((bh * 8 + nc) * 80 + dp) * 256 + m] = acc2[fa][fb][r];
      }
    }
}

__global__ __launch_bounds__(256) void k_kv_reduce(
    const float* __restrict__ KVP, float* __restrict__ KVT)
{
  int idx = blockIdx.x * 256 + threadIdx.x;
  if (idx >= 32 * 80 * 256) return;
  int bh = idx / (80 * 256);
  int rem = idx % (80 * 256);
  float s = 0.f;
#pragma unroll
  for (int nci = 0; nci < 8; ++nci) s += KVP[(size_t)(bh * 8 + nci) * 80 * 256 + rem];
  KVT[idx] = s;
}

// ---------------- phi_q: exp(q.omega^T - 0.5||q||^2)/16 -> PHIQ ----------------
__global__ __launch_bounds__(256) void k_phi_q(
    const float* __restrict__ QF, const float* __restrict__ omega,
    unsigned short* __restrict__ PHIQ)
{
  __shared__ unsigned short AHs[64][72], ALs[64][72];
  __shared__ unsigned short OH[256][72], OL[256][72];
  __shared__ float norm_s[64];
  const int nt = blockIdx.x;   // 0..63
  const int bh = blockIdx.y;   // 0..31
  const int t = threadIdx.x, w = t >> 6, l = t & 63;
  const int b = bh >> 4, h = bh & 15;
  {
    int r = t >> 2, cq = (t & 3) * 4;
    float ss = 0.f;
#pragma unroll
    for (int j = 0; j < 4; ++j) {
      int c = cq + 16 * j;
      fvec4 v = *(const fvec4*)&QF[(size_t)(b * 4096 + nt * 64 + r) * 1024 + h * 64 + c];
      s16x4 hv, lv;
#pragma unroll
      for (int i = 0; i < 4; ++i) {
        unsigned short hs = f2bf_rn(v[i]);
        hv[i] = (short)hs;
        lv[i] = (short)f2bf_rn(v[i] - bf2f(hs));
        ss += v[i] * v[i];
      }
      *(s16x4*)&AHs[r][c] = hv;
      *(s16x4*)&ALs[r][c] = lv;
    }
    ss += __shfl_xor(ss, 1);
    ss += __shfl_xor(ss, 2);
    if ((t & 3) == 0) norm_s[r] = 0.5f * ss;
  }
#pragma unroll
  for (int j = 0; j < 16; ++j) {
    int e = j * 256 + t;
    int m = e >> 4, c = (e & 15) * 4;
    fvec4 v = *(const fvec4*)&omega[m * 64 + c];
    s16x4 hv, lv;
#pragma unroll
    for (int i = 0; i < 4; ++i) {
      unsigned short hs = f2bf_rn(v[i]);
      hv[i] = (short)hs;
      lv[i] = (short)f2bf_rn(v[i] - bf2f(hs));
    }
    *(s16x4*)&OH[m][c] = hv;
    *(s16x4*)&OL[m][c] = lv;
  }
  __syncthreads();
  f32x4 acc[4][4];
#pragma unroll
  for (int a = 0; a < 4; ++a)
#pragma unroll
    for (int bb = 0; bb < 4; ++bb) acc[a][bb] = (f32x4)0.f;
  const int lr = l & 15, ko8 = (l >> 4) * 8;
#pragma unroll
  for (int ksub = 0; ksub < 2; ++ksub) {
    int ko = ksub * 32 + ko8;
    s16x8 ah[4], al[4], bh[4], bl[4];
#pragma unroll
    for (int f = 0; f < 4; ++f) {
      ah[f] = *(const s16x8*)&AHs[f * 16 + lr][ko];
      al[f] = *(const s16x8*)&ALs[f * 16 + lr][ko];
      bh[f] = *(const s16x8*)&OH[w * 64 + f * 16 + lr][ko];
      bl[f] = *(const s16x8*)&OL[w * 64 + f * 16 + lr][ko];
    }
#pragma unroll
    for (int fa = 0; fa < 4; ++fa)
#pragma unroll
      for (int fb = 0; fb < 4; ++fb) {
        acc[fa][fb] = mfma16(ah[fa], bh[fb], acc[fa][fb]);
        acc[fa][fb] = mfma16(ah[fa], bl[fb], acc[fa][fb]);
        acc[fa][fb] = mfma16(al[fa], bh[fb], acc[fa][fb]);
      }
  }
  const int lg = l >> 4;
#pragma unroll
  for (int fa = 0; fa < 4; ++fa)
#pragma unroll
    for (int r = 0; r < 4; ++r) {
      int n = fa * 16 + lg * 4 + r;
      float nm = norm_s[n];
#pragma unroll
      for (int fb = 0; fb < 4; ++fb) {
        int m = w * 64 + fb * 16 + lr;
        float p = __expf(acc[fa][fb][r] - nm) * 0.0625f;
        PHIQ[(size_t)(bh * 4096 + nt * 64 + n) * 256 + m] = f2bf_rn(p);
      }
    }
}

// ---------------- attn: out = (phi_q @ kv) * z ----------------
__global__ __launch_bounds__(256) void k_attn(
    const unsigned short* __restrict__ PHIQ,
    const float* __restrict__ KVT,
    unsigned short* __restrict__ ATT)
{
  __shared__ unsigned short KVB[80][264];
  __shared__ unsigned short PH[128][40];
  const int ntile = blockIdx.x;  // 0..31
  const int bh = blockIdx.y;     // 0..31
  const int b = bh >> 4, h = bh & 15;
  const int t = threadIdx.x, w = t >> 6, l = t & 63;
#pragma unroll
  for (int j = 0; j < 20; ++j) {
    int e = (j * 256 + t) * 4;
    int dp = e >> 8, m = e & 255;
    fvec4 v = *(const fvec4*)&KVT[(size_t)bh * 80 * 256 + dp * 256 + m];
    s16x4 hv;
#pragma unroll
    for (int i = 0; i < 4; ++i) hv[i] = (short)f2bf_rn(v[i]);
    *(s16x4*)&KVB[dp][m] = hv;
  }
  __syncthreads();
  f32x4 acc[2][5];
#pragma unroll
  for (int a = 0; a < 2; ++a)
#pragma unroll
    for (int bb = 0; bb < 5; ++bb) acc[a][bb] = (f32x4)0.f;
  for (int ks = 0; ks < 8; ++ks) {
    const int m0 = ks * 32;
#pragma unroll
    for (int j = 0; j < 2; ++j) {
      int n = t >> 1, c = (t & 1) * 8 + j * 16;
      *(s16x8*)&PH[n][c] =
          *(const s16x8*)&PHIQ[(size_t)(bh * 4096 + ntile * 128 + n) * 256 + m0 + c];
    }
    __syncthreads();
    const int lr = l & 15, ko = (l >> 4) * 8;
    s16x8 fA[2], fB[5];
#pragma unroll
    for (int f = 0; f < 2; ++f) fA[f] = *(const s16x8*)&PH[w * 32 + f * 16 + lr][ko];
#pragma unroll
    for (int f = 0; f < 5; ++f) fB[f] = *(const s16x8*)&KVB[f * 16 + lr][m0 + ko];
#pragma unroll
    for (int fa = 0; fa < 2; ++fa)
#pragma unroll
      for (int fb = 0; fb < 5; ++fb) acc[fa][fb] = mfma16(fA[fa], fB[fb], acc[fa][fb]);
    __syncthreads();
  }
  const int lr = l & 15, lg = l >> 4;
#pragma unroll
  for (int fa = 0; fa < 2; ++fa)
#pragma unroll
    for (int r = 0; r < 4; ++r) {
      float den = __shfl(acc[fa][4][r], (l & 48));
      float z = 1.f / (den + 1e-6f);
      int n = ntile * 128 + w * 32 + fa * 16 + lg * 4 + r;
#pragma unroll
      for (int fb = 0; fb < 4; ++fb) {
        int col = h * 64 + fb * 16 + lr;
        ATT[(size_t)(b * 4096 + n) * 1024 + col] = f2bf_rn(acc[fa][fb][r] * z);
      }
    }
}

// ---------------- final GEMM: out = attn @ w_o + b_o ----------------
__global__ __launch_bounds__(256) void k_gemm_out(
    const unsigned short* __restrict__ ATT,
    const unsigned short* __restrict__ WOT,
    const float* __restrict__ b_o,
    float* __restrict__ OUT)
{
  __shared__ unsigned short As[128][40], Bs[128][40];
  const int cb = blockIdx.x;  // 0..7
  const int rb = blockIdx.y;  // 0..63
  const int t = threadIdx.x, w = t >> 6, l = t & 63;
  f32x4 acc[4][4];
#pragma unroll
  for (int a = 0; a < 4; ++a)
#pragma unroll
    for (int bb = 0; bb < 4; ++bb) acc[a][bb] = (f32x4)0.f;
  for (int ks = 0; ks < 32; ++ks) {
    const int k0 = ks * 32;
#pragma unroll
    for (int j = 0; j < 2; ++j) {
      int r = t >> 1, c = (t & 1) * 8 + j * 16;
      *(s16x8*)&As[r][c] = *(const s16x8*)&ATT[(size_t)(rb * 128 + r) * 1024 + k0 + c];
      *(s16x8*)&Bs[r][c] = *(const s16x8*)&WOT[(size_t)(cb * 128 + r) * 1024 + k0 + c];
    }
    __syncthreads();
    const int wm = (w & 1) * 64, wn = (w >> 1) * 64, lr = l & 15, ko = (l >> 4) * 8;
    s16x8 fA[4], fB[4];
#pragma unroll
    for (int f = 0; f < 4; ++f) {
      fA[f] = *(const s16x8*)&As[wm + f * 16 + lr][ko];
      fB[f] = *(const s16x8*)&Bs[wn + f * 16 + lr][ko];
    }
#pragma unroll
    for (int fa = 0; fa < 4; ++fa)
#pragma unroll
      for (int fb = 0; fb < 4; ++fb) acc[fa][fb] = mfma16(fA[fa], fB[fb], acc[fa][fb]);
    __syncthreads();
  }
  const int wm = (w & 1) * 64, wn = (w >> 1) * 64, lr = l & 15, lg = l >> 4;
#pragma unroll
  for (int fa = 0; fa < 4; ++fa)
#pragma unroll
    for (int r = 0; r < 4; ++r) {
      int row = rb * 128 + wm + fa * 16 + lg * 4 + r;
#pragma unroll
      for (int fb = 0; fb < 4; ++fb) {
        int col = cb * 128 + wn + fb * 16 + lr;
        OUT[(size_t)row * 1024 + col] = acc[fa][fb][r] + b_o[col];
      }
    }
}

extern "C" void kernel_launch(void* const* d_in, const int* in_sizes, int n_in,
                              void* d_out, int out_size, void* d_ws, size_t ws_size,
                              hipStream_t stream)
{
  const float* x  = (const float*)d_in[0];
  const float* wq = (const float*)d_in[1];
  const float* wk = (const float*)d_in[2];
  const float* wv = (const float*)d_in[3];
  const float* wo = (const float*)d_in[4];
  const float* bo = (const float*)d_in[5];
  const float* om = (const float*)d_in[6];
  float* out = (float*)d_out;

  // Workspace layout with lifetime-based reuse (total 126,353,408 B):
  //  A: WOT    [0, 2 MB)                       live prep..out
  //  B: QF     [A_end, +33.5 MB)               live qkv..phi_q; ATT reuses after
  //  C: KF+VB  [B_end, +67 MB)                 live qkv..phik_kv; PHIQ reuses after
  //  D: WTh/WTl[C_end, +21 MB)                 live prep..qkv;   KVP reuses after
  //  E: KVT    [D_end, +2.6 MB)                live reduce..attn
  char* ws = (char*)d_ws;
  size_t o = 0;
  unsigned short* WOT = (unsigned short*)(ws + o); o += (size_t)1024 * 1024 * 2;
  char* segB = ws + o;                             o += (size_t)8192 * 1024 * 4;
  char* segC = ws + o;                             o += (size_t)8192 * 1024 * 4 + (size_t)8192 * 1024 * 2;
  char* segD = ws + o;                             o += (size_t)32 * 8 * 80 * 256 * 4;
  float* KVT = (float*)(ws + o);                   o += (size_t)32 * 80 * 256 * 4;

  float*          QF   = (float*)segB;
  unsigned short* ATT  = (unsigned short*)segB;   // reuses B after phi_q
  float*          KF   = (float*)segC;
  unsigned short* VB   = (unsigned short*)(segC + (size_t)8192 * 1024 * 4);
  unsigned short* PHIQ = (unsigned short*)segC;   // reuses C after phik_kv
  unsigned short* WTh  = (unsigned short*)segD;
  unsigned short* WTl  = (unsigned short*)(segD + (size_t)3072 * 1024 * 2);
  float*          KVP  = (float*)segD;            // reuses D after qkv

  k_prep_w<<<dim3(16, 16, 4), 256, 0, stream>>>(wq, wk, wv, wo, WTh, WTl, WOT);
  k_gemm_qkv<<<dim3(24, 64), 256, 0, stream>>>(x, WTh, WTl, QF, KF, VB);
  k_phik_kv<<<dim3(8, 32), 256, 0, stream>>>(KF, VB, om, KVP);
  k_kv_reduce<<<dim3(2560), 256, 0, stream>>>(KVP, KVT);
  k_phi_q<<<dim3(64, 32), 256, 0, stream>>>(QF, om, PHIQ);
  k_attn<<<dim3(32, 32), 256, 0, stream>>>(PHIQ, KVT, ATT);
  k_gemm_out<<<dim3(8, 64), 256, 0, stream>>>(ATT, WOT, bo, out);
}

// Round 3
// 303.657 us; speedup vs baseline: 1.0881x; 1.0881x over previous
//
#include <hip/hip_runtime.h>

#define DEVI __device__ __forceinline__

using f32x4 = __attribute__((ext_vector_type(4))) float;
using fvec4 = __attribute__((ext_vector_type(4))) float;
using s16x4 = __attribute__((ext_vector_type(4))) short;
using s16x8 = __attribute__((ext_vector_type(8))) short;

DEVI unsigned short f2bf_rn(float f) {
  union { float f; unsigned u; } v; v.f = f;
  unsigned r = v.u + 0x7fffu + ((v.u >> 16) & 1u);
  return (unsigned short)(r >> 16);
}
DEVI float bf2f(unsigned short h) {
  union { unsigned u; float f; } v; v.u = ((unsigned)h) << 16;
  return v.f;
}
DEVI f32x4 mfma16(s16x8 a, s16x8 b, f32x4 c) {
  return __builtin_amdgcn_mfma_f32_16x16x32_bf16(a, b, c, 0, 0, 0);
}

// ---------------- split X f32 -> bf16 hi/lo (once) ----------------
__global__ __launch_bounds__(256) void k_split_x(
    const float* __restrict__ X,
    unsigned short* __restrict__ XH, unsigned short* __restrict__ XL)
{
  size_t i = ((size_t)blockIdx.x * 256 + threadIdx.x) * 8;
  fvec4 a = *(const fvec4*)&X[i];
  fvec4 b = *(const fvec4*)&X[i + 4];
  s16x8 hv, lv;
#pragma unroll
  for (int j = 0; j < 4; ++j) {
    unsigned short h = f2bf_rn(a[j]);
    hv[j] = (short)h; lv[j] = (short)f2bf_rn(a[j] - bf2f(h));
  }
#pragma unroll
  for (int j = 0; j < 4; ++j) {
    unsigned short h = f2bf_rn(b[j]);
    hv[4 + j] = (short)h; lv[4 + j] = (short)f2bf_rn(b[j] - bf2f(h));
  }
  *(s16x8*)&XH[i] = hv;
  *(s16x8*)&XL[i] = lv;
}

// ---------------- prep: transpose + split weights ----------------
__global__ __launch_bounds__(256) void k_prep_w(
    const float* __restrict__ wq, const float* __restrict__ wk,
    const float* __restrict__ wv, const float* __restrict__ wo,
    unsigned short* __restrict__ WTh, unsigned short* __restrict__ WTl,
    unsigned short* __restrict__ WOT)
{
  __shared__ float tile[64][65];
  const int z = blockIdx.z;
  const float* src = (z == 0) ? wq : (z == 1) ? wk : (z == 2) ? wv : wo;
  const int k0 = blockIdx.x * 64;
  const int n0 = blockIdx.y * 64;
  const int t = threadIdx.x;
#pragma unroll
  for (int j = 0; j < 4; ++j) {
    int r = (t >> 4) + 16 * j;
    int c = (t & 15) * 4;
    fvec4 v = *(const fvec4*)&src[(size_t)(k0 + r) * 1024 + n0 + c];
#pragma unroll
    for (int i = 0; i < 4; ++i) tile[r][c + i] = v[i];
  }
  __syncthreads();
#pragma unroll
  for (int j = 0; j < 4; ++j) {
    int n = (t >> 4) + 16 * j;
    int kc = (t & 15) * 4;
    s16x4 hv, lv;
#pragma unroll
    for (int i = 0; i < 4; ++i) {
      float f = tile[kc + i][n];
      unsigned short hs = f2bf_rn(f);
      hv[i] = (short)hs;
      lv[i] = (short)f2bf_rn(f - bf2f(hs));
    }
    if (z < 3) {
      size_t o = (size_t)(z * 1024 + n0 + n) * 1024 + k0 + kc;
      *(s16x4*)&WTh[o] = hv;
      *(s16x4*)&WTl[o] = lv;
    } else {
      *(s16x4*)&WOT[(size_t)(n0 + n) * 1024 + k0 + kc] = hv;
    }
  }
}

// ---------------- QKV GEMM: pure-copy staging, 3-pass for q,k ----------------
__global__ __launch_bounds__(256) void k_gemm_qkv(
    const unsigned short* __restrict__ XH, const unsigned short* __restrict__ XL,
    const unsigned short* __restrict__ WTh, const unsigned short* __restrict__ WTl,
    unsigned short* __restrict__ QH, unsigned short* __restrict__ QL,
    unsigned short* __restrict__ KH, unsigned short* __restrict__ KL,
    unsigned short* __restrict__ VB)
{
  __shared__ unsigned short AH[128][40], AL[128][40], BH[128][40], BL[128][40];
  const int cb = blockIdx.x;  // 0..23
  const int rb = blockIdx.y;  // 0..63
  const int t = threadIdx.x;
  const int w = t >> 6, l = t & 63;
  const bool tp = (cb < 16);
  f32x4 acc[4][4];
#pragma unroll
  for (int a = 0; a < 4; ++a)
#pragma unroll
    for (int b = 0; b < 4; ++b) acc[a][b] = (f32x4)0.f;

  for (int ks = 0; ks < 32; ++ks) {
    const int k0 = ks * 32;
    // stage A: [128][32] copy from XH/XL
    {
      int r = t >> 1, c = (t & 1) * 16;
      size_t o = (size_t)(rb * 128 + r) * 1024 + k0 + c;
      *(s16x8*)&AH[r][c]     = *(const s16x8*)&XH[o];
      *(s16x8*)&AH[r][c + 8] = *(const s16x8*)&XH[o + 8];
      if (tp) {
        *(s16x8*)&AL[r][c]     = *(const s16x8*)&XL[o];
        *(s16x8*)&AL[r][c + 8] = *(const s16x8*)&XL[o + 8];
      }
    }
    // stage B: [128][32] copy from WTh/WTl
    {
      int r = t >> 1, c = (t & 1) * 16;
      size_t o = (size_t)(cb * 128 + r) * 1024 + k0 + c;
      *(s16x8*)&BH[r][c]     = *(const s16x8*)&WTh[o];
      *(s16x8*)&BH[r][c + 8] = *(const s16x8*)&WTh[o + 8];
      if (tp) {
        *(s16x8*)&BL[r][c]     = *(const s16x8*)&WTl[o];
        *(s16x8*)&BL[r][c + 8] = *(const s16x8*)&WTl[o + 8];
      }
    }
    __syncthreads();
    const int wm = (w & 1) * 64, wn = (w >> 1) * 64;
    const int lr = l & 15, ko = (l >> 4) * 8;
    s16x8 ah[4], al[4], bh[4], bl[4];
#pragma unroll
    for (int f = 0; f < 4; ++f) {
      ah[f] = *(const s16x8*)&AH[wm + f * 16 + lr][ko];
      bh[f] = *(const s16x8*)&BH[wn + f * 16 + lr][ko];
    }
    if (tp) {
#pragma unroll
      for (int f = 0; f < 4; ++f) {
        al[f] = *(const s16x8*)&AL[wm + f * 16 + lr][ko];
        bl[f] = *(const s16x8*)&BL[wn + f * 16 + lr][ko];
      }
    }
#pragma unroll
    for (int fa = 0; fa < 4; ++fa)
#pragma unroll
      for (int fb = 0; fb < 4; ++fb) {
        acc[fa][fb] = mfma16(ah[fa], bh[fb], acc[fa][fb]);
        if (tp) {
          acc[fa][fb] = mfma16(ah[fa], bl[fb], acc[fa][fb]);
          acc[fa][fb] = mfma16(al[fa], bh[fb], acc[fa][fb]);
        }
      }
    __syncthreads();
  }
  const int wm = (w & 1) * 64, wn = (w >> 1) * 64;
  const int lr = l & 15, lg = l >> 4;
#pragma unroll
  for (int fa = 0; fa < 4; ++fa)
#pragma unroll
    for (int r = 0; r < 4; ++r) {
      int row = rb * 128 + wm + fa * 16 + lg * 4 + r;
#pragma unroll
      for (int fb = 0; fb < 4; ++fb) {
        int col = cb * 128 + wn + fb * 16 + lr;
        float v = acc[fa][fb][r];
        unsigned short hs = f2bf_rn(v);
        if (cb < 8) {
          QH[(size_t)row * 1024 + col] = hs;
          QL[(size_t)row * 1024 + col] = f2bf_rn(v - bf2f(hs));
        } else if (cb < 16) {
          KH[(size_t)row * 1024 + col - 1024] = hs;
          KL[(size_t)row * 1024 + col - 1024] = f2bf_rn(v - bf2f(hs));
        } else {
          VB[(size_t)row * 1024 + col - 2048] = hs;
        }
      }
    }
}

// ---------------- fused phi_k + kv ----------------
__global__ __launch_bounds__(256, 1) void k_phik_kv(
    const unsigned short* __restrict__ KH, const unsigned short* __restrict__ KL,
    const unsigned short* __restrict__ VB,
    const float* __restrict__ omega, float* __restrict__ KVP)
{
  __shared__ unsigned short OH[256][72], OL[256][72];
  __shared__ unsigned short KHs[64][72], KLs[64][72];
  __shared__ unsigned short PKT[256][72];
  __shared__ unsigned short AVT[80][72];
  __shared__ float norm_s[64];
  const int nc = blockIdx.x;  // 0..7
  const int bh = blockIdx.y;  // 0..31
  const int b = bh >> 4, h = bh & 15;
  const int t = threadIdx.x, w = t >> 6, l = t & 63;
  const int lr = l & 15, lg = l >> 4, ko8 = lg * 8;

  // stage omega hi/lo once
#pragma unroll
  for (int j = 0; j < 16; ++j) {
    int e = j * 256 + t;
    int m = e >> 4, c = (e & 15) * 4;
    fvec4 v = *(const fvec4*)&omega[m * 64 + c];
    s16x4 hv, lv;
#pragma unroll
    for (int i = 0; i < 4; ++i) {
      unsigned short hs = f2bf_rn(v[i]);
      hv[i] = (short)hs;
      lv[i] = (short)f2bf_rn(v[i] - bf2f(hs));
    }
    *(s16x4*)&OH[m][c] = hv;
    *(s16x4*)&OL[m][c] = lv;
  }
  for (int e = t; e < 16 * 64; e += 256) {
    int rr = e >> 6, cc = e & 63;
    AVT[64 + rr][cc] = (rr == 0) ? (unsigned short)0x3F80 : (unsigned short)0;
  }

  f32x4 acc2[5][4];
#pragma unroll
  for (int a = 0; a < 5; ++a)
#pragma unroll
    for (int bb = 0; bb < 4; ++bb) acc2[a][bb] = (f32x4)0.f;

  for (int st = 0; st < 8; ++st) {
    const int n0 = nc * 512 + st * 64;
    __syncthreads();
    // stage K tile hi/lo (copy) + row norms
    {
      int r = t >> 2, cq = (t & 3) * 4;
      float ss = 0.f;
#pragma unroll
      for (int j = 0; j < 4; ++j) {
        int c = cq + 16 * j;
        size_t o = (size_t)(b * 4096 + n0 + r) * 1024 + h * 64 + c;
        s16x4 vh = *(const s16x4*)&KH[o];
        s16x4 vl = *(const s16x4*)&KL[o];
        *(s16x4*)&KHs[r][c] = vh;
        *(s16x4*)&KLs[r][c] = vl;
#pragma unroll
        for (int i = 0; i < 4; ++i) {
          float q = bf2f((unsigned short)vh[i]) + bf2f((unsigned short)vl[i]);
          ss += q * q;
        }
      }
      ss += __shfl_xor(ss, 1);
      ss += __shfl_xor(ss, 2);
      if ((t & 3) == 0) norm_s[r] = 0.5f * ss;
    }
    // stage v^T
    {
      int n = t >> 2, dq = (t & 3) * 16;
      s16x8 v0 = *(const s16x8*)&VB[(size_t)(b * 4096 + n0 + n) * 1024 + h * 64 + dq];
      s16x8 v1 = *(const s16x8*)&VB[(size_t)(b * 4096 + n0 + n) * 1024 + h * 64 + dq + 8];
#pragma unroll
      for (int i = 0; i < 8; ++i) {
        AVT[dq + i][n] = (unsigned short)v0[i];
        AVT[dq + 8 + i][n] = (unsigned short)v1[i];
      }
    }
    __syncthreads();
    // proj MFMA 3-pass
    f32x4 acc[4][4];
#pragma unroll
    for (int a = 0; a < 4; ++a)
#pragma unroll
      for (int bb = 0; bb < 4; ++bb) acc[a][bb] = (f32x4)0.f;
#pragma unroll
    for (int ksub = 0; ksub < 2; ++ksub) {
      int ko = ksub * 32 + ko8;
      s16x8 ah[4], al[4], bh[4], bl[4];
#pragma unroll
      for (int f = 0; f < 4; ++f) {
        ah[f] = *(const s16x8*)&KHs[f * 16 + lr][ko];
        al[f] = *(const s16x8*)&KLs[f * 16 + lr][ko];
        bh[f] = *(const s16x8*)&OH[w * 64 + f * 16 + lr][ko];
        bl[f] = *(const s16x8*)&OL[w * 64 + f * 16 + lr][ko];
      }
#pragma unroll
      for (int fa = 0; fa < 4; ++fa)
#pragma unroll
        for (int fb = 0; fb < 4; ++fb) {
          acc[fa][fb] = mfma16(ah[fa], bh[fb], acc[fa][fb]);
          acc[fa][fb] = mfma16(ah[fa], bl[fb], acc[fa][fb]);
          acc[fa][fb] = mfma16(al[fa], bh[fb], acc[fa][fb]);
        }
    }
    // exp -> phi_k transposed into PKT[m][n]
#pragma unroll
    for (int fa = 0; fa < 4; ++fa)
#pragma unroll
      for (int r = 0; r < 4; ++r) {
        int n = fa * 16 + lg * 4 + r;
        float nm = norm_s[n];
#pragma unroll
        for (int fb = 0; fb < 4; ++fb) {
          int m = w * 64 + fb * 16 + lr;
          float p = __expf(acc[fa][fb][r] - nm) * 0.0625f;
          PKT[m][n] = f2bf_rn(p);
        }
      }
    __syncthreads();
    // kv MFMA over n
#pragma unroll
    for (int ksub = 0; ksub < 2; ++ksub) {
      int ko = ksub * 32 + ko8;
      s16x8 fA[5], fB[4];
#pragma unroll
      for (int f = 0; f < 5; ++f) fA[f] = *(const s16x8*)&AVT[f * 16 + lr][ko];
#pragma unroll
      for (int f = 0; f < 4; ++f) fB[f] = *(const s16x8*)&PKT[w * 64 + f * 16 + lr][ko];
#pragma unroll
      for (int fa = 0; fa < 5; ++fa)
#pragma unroll
        for (int fb = 0; fb < 4; ++fb) acc2[fa][fb] = mfma16(fA[fa], fB[fb], acc2[fa][fb]);
    }
  }
#pragma unroll
  for (int fa = 0; fa < 5; ++fa)
#pragma unroll
    for (int r = 0; r < 4; ++r) {
      int dp = fa * 16 + lg * 4 + r;
#pragma unroll
      for (int fb = 0; fb < 4; ++fb) {
        int m = w * 64 + fb * 16 + lr;
        KVP[(size_t)((bh * 8 + nc) * 80 + dp) * 256 + m] = acc2[fa][fb][r];
      }
    }
}

__global__ __launch_bounds__(256) void k_kv_reduce(
    const float* __restrict__ KVP, float* __restrict__ KVT)
{
  int idx = blockIdx.x * 256 + threadIdx.x;
  if (idx >= 32 * 80 * 256) return;
  int bh = idx / (80 * 256);
  int rem = idx % (80 * 256);
  float s = 0.f;
#pragma unroll
  for (int nci = 0; nci < 8; ++nci) s += KVP[(size_t)(bh * 8 + nci) * 80 * 256 + rem];
  KVT[idx] = s;
}

// ---------------- phi_q ----------------
__global__ __launch_bounds__(256) void k_phi_q(
    const unsigned short* __restrict__ QH, const unsigned short* __restrict__ QL,
    const float* __restrict__ omega,
    unsigned short* __restrict__ PHIQ)
{
  __shared__ unsigned short AHs[64][72], ALs[64][72];
  __shared__ unsigned short OH[256][72], OL[256][72];
  __shared__ float norm_s[64];
  const int nt = blockIdx.x;   // 0..63
  const int bh = blockIdx.y;   // 0..31
  const int t = threadIdx.x, w = t >> 6, l = t & 63;
  const int b = bh >> 4, h = bh & 15;
  {
    int r = t >> 2, cq = (t & 3) * 4;
    float ss = 0.f;
#pragma unroll
    for (int j = 0; j < 4; ++j) {
      int c = cq + 16 * j;
      size_t o = (size_t)(b * 4096 + nt * 64 + r) * 1024 + h * 64 + c;
      s16x4 vh = *(const s16x4*)&QH[o];
      s16x4 vl = *(const s16x4*)&QL[o];
      *(s16x4*)&AHs[r][c] = vh;
      *(s16x4*)&ALs[r][c] = vl;
#pragma unroll
      for (int i = 0; i < 4; ++i) {
        float q = bf2f((unsigned short)vh[i]) + bf2f((unsigned short)vl[i]);
        ss += q * q;
      }
    }
    ss += __shfl_xor(ss, 1);
    ss += __shfl_xor(ss, 2);
    if ((t & 3) == 0) norm_s[r] = 0.5f * ss;
  }
#pragma unroll
  for (int j = 0; j < 16; ++j) {
    int e = j * 256 + t;
    int m = e >> 4, c = (e & 15) * 4;
    fvec4 v = *(const fvec4*)&omega[m * 64 + c];
    s16x4 hv, lv;
#pragma unroll
    for (int i = 0; i < 4; ++i) {
      unsigned short hs = f2bf_rn(v[i]);
      hv[i] = (short)hs;
      lv[i] = (short)f2bf_rn(v[i] - bf2f(hs));
    }
    *(s16x4*)&OH[m][c] = hv;
    *(s16x4*)&OL[m][c] = lv;
  }
  __syncthreads();
  f32x4 acc[4][4];
#pragma unroll
  for (int a = 0; a < 4; ++a)
#pragma unroll
    for (int bb = 0; bb < 4; ++bb) acc[a][bb] = (f32x4)0.f;
  const int lr = l & 15, ko8 = (l >> 4) * 8;
#pragma unroll
  for (int ksub = 0; ksub < 2; ++ksub) {
    int ko = ksub * 32 + ko8;
    s16x8 ah[4], al[4], bh[4], bl[4];
#pragma unroll
    for (int f = 0; f < 4; ++f) {
      ah[f] = *(const s16x8*)&AHs[f * 16 + lr][ko];
      al[f] = *(const s16x8*)&ALs[f * 16 + lr][ko];
      bh[f] = *(const s16x8*)&OH[w * 64 + f * 16 + lr][ko];
      bl[f] = *(const s16x8*)&OL[w * 64 + f * 16 + lr][ko];
    }
#pragma unroll
    for (int fa = 0; fa < 4; ++fa)
#pragma unroll
      for (int fb = 0; fb < 4; ++fb) {
        acc[fa][fb] = mfma16(ah[fa], bh[fb], acc[fa][fb]);
        acc[fa][fb] = mfma16(ah[fa], bl[fb], acc[fa][fb]);
        acc[fa][fb] = mfma16(al[fa], bh[fb], acc[fa][fb]);
      }
  }
  const int lg = l >> 4;
#pragma unroll
  for (int fa = 0; fa < 4; ++fa)
#pragma unroll
    for (int r = 0; r < 4; ++r) {
      int n = fa * 16 + lg * 4 + r;
      float nm = norm_s[n];
#pragma unroll
      for (int fb = 0; fb < 4; ++fb) {
        int m = w * 64 + fb * 16 + lr;
        float p = __expf(acc[fa][fb][r] - nm) * 0.0625f;
        PHIQ[(size_t)(bh * 4096 + nt * 64 + n) * 256 + m] = f2bf_rn(p);
      }
    }
}

// ---------------- attn: out = (phi_q @ kv) * z ----------------
__global__ __launch_bounds__(256) void k_attn(
    const unsigned short* __restrict__ PHIQ,
    const float* __restrict__ KVT,
    unsigned short* __restrict__ ATT)
{
  __shared__ unsigned short KVB[80][264];
  __shared__ unsigned short PH[128][40];
  const int ntile = blockIdx.x;  // 0..31
  const int bh = blockIdx.y;     // 0..31
  const int b = bh >> 4, h = bh & 15;
  const int t = threadIdx.x, w = t >> 6, l = t & 63;
#pragma unroll
  for (int j = 0; j < 20; ++j) {
    int e = (j * 256 + t) * 4;
    int dp = e >> 8, m = e & 255;
    fvec4 v = *(const fvec4*)&KVT[(size_t)bh * 80 * 256 + dp * 256 + m];
    s16x4 hv;
#pragma unroll
    for (int i = 0; i < 4; ++i) hv[i] = (short)f2bf_rn(v[i]);
    *(s16x4*)&KVB[dp][m] = hv;
  }
  __syncthreads();
  f32x4 acc[2][5];
#pragma unroll
  for (int a = 0; a < 2; ++a)
#pragma unroll
    for (int bb = 0; bb < 5; ++bb) acc[a][bb] = (f32x4)0.f;
  for (int ks = 0; ks < 8; ++ks) {
    const int m0 = ks * 32;
#pragma unroll
    for (int j = 0; j < 2; ++j) {
      int n = t >> 1, c = (t & 1) * 8 + j * 16;
      *(s16x8*)&PH[n][c] =
          *(const s16x8*)&PHIQ[(size_t)(bh * 4096 + ntile * 128 + n) * 256 + m0 + c];
    }
    __syncthreads();
    const int lr = l & 15, ko = (l >> 4) * 8;
    s16x8 fA[2], fB[5];
#pragma unroll
    for (int f = 0; f < 2; ++f) fA[f] = *(const s16x8*)&PH[w * 32 + f * 16 + lr][ko];
#pragma unroll
    for (int f = 0; f < 5; ++f) fB[f] = *(const s16x8*)&KVB[f * 16 + lr][m0 + ko];
#pragma unroll
    for (int fa = 0; fa < 2; ++fa)
#pragma unroll
      for (int fb = 0; fb < 5; ++fb) acc[fa][fb] = mfma16(fA[fa], fB[fb], acc[fa][fb]);
    __syncthreads();
  }
  const int lr = l & 15, lg = l >> 4;
#pragma unroll
  for (int fa = 0; fa < 2; ++fa)
#pragma unroll
    for (int r = 0; r < 4; ++r) {
      float den = __shfl(acc[fa][4][r], (l & 48));
      float z = 1.f / (den + 1e-6f);
      int n = ntile * 128 + w * 32 + fa * 16 + lg * 4 + r;
#pragma unroll
      for (int fb = 0; fb < 4; ++fb) {
        int col = h * 64 + fb * 16 + lr;
        ATT[(size_t)(b * 4096 + n) * 1024 + col] = f2bf_rn(acc[fa][fb][r] * z);
      }
    }
}

// ---------------- final GEMM: out = attn @ w_o + b_o ----------------
__global__ __launch_bounds__(256) void k_gemm_out(
    const unsigned short* __restrict__ ATT,
    const unsigned short* __restrict__ WOT,
    const float* __restrict__ b_o,
    float* __restrict__ OUT)
{
  __shared__ unsigned short As[128][40], Bs[128][40];
  const int cb = blockIdx.x;  // 0..7
  const int rb = blockIdx.y;  // 0..63
  const int t = threadIdx.x, w = t >> 6, l = t & 63;
  f32x4 acc[4][4];
#pragma unroll
  for (int a = 0; a < 4; ++a)
#pragma unroll
    for (int bb = 0; bb < 4; ++bb) acc[a][bb] = (f32x4)0.f;
  for (int ks = 0; ks < 32; ++ks) {
    const int k0 = ks * 32;
#pragma unroll
    for (int j = 0; j < 2; ++j) {
      int r = t >> 1, c = (t & 1) * 8 + j * 16;
      *(s16x8*)&As[r][c] = *(const s16x8*)&ATT[(size_t)(rb * 128 + r) * 1024 + k0 + c];
      *(s16x8*)&Bs[r][c] = *(const s16x8*)&WOT[(size_t)(cb * 128 + r) * 1024 + k0 + c];
    }
    __syncthreads();
    const int wm = (w & 1) * 64, wn = (w >> 1) * 64, lr = l & 15, ko = (l >> 4) * 8;
    s16x8 fA[4], fB[4];
#pragma unroll
    for (int f = 0; f < 4; ++f) {
      fA[f] = *(const s16x8*)&As[wm + f * 16 + lr][ko];
      fB[f] = *(const s16x8*)&Bs[wn + f * 16 + lr][ko];
    }
#pragma unroll
    for (int fa = 0; fa < 4; ++fa)
#pragma unroll
      for (int fb = 0; fb < 4; ++fb) acc[fa][fb] = mfma16(fA[fa], fB[fb], acc[fa][fb]);
    __syncthreads();
  }
  const int wm = (w & 1) * 64, wn = (w >> 1) * 64, lr = l & 15, lg = l >> 4;
#pragma unroll
  for (int fa = 0; fa < 4; ++fa)
#pragma unroll
    for (int r = 0; r < 4; ++r) {
      int row = rb * 128 + wm + fa * 16 + lg * 4 + r;
#pragma unroll
      for (int fb = 0; fb < 4; ++fb) {
        int col = cb * 128 + wn + fb * 16 + lr;
        OUT[(size_t)row * 1024 + col] = acc[fa][fb][r] + b_o[col];
      }
    }
}

extern "C" void kernel_launch(void* const* d_in, const int* in_sizes, int n_in,
                              void* d_out, int out_size, void* d_ws, size_t ws_size,
                              hipStream_t stream)
{
  const float* x  = (const float*)d_in[0];
  const float* wq = (const float*)d_in[1];
  const float* wk = (const float*)d_in[2];
  const float* wv = (const float*)d_in[3];
  const float* wo = (const float*)d_in[4];
  const float* bo = (const float*)d_in[5];
  const float* om = (const float*)d_in[6];
  float* out = (float*)d_out;

  // Workspace (total 132,120,576 B ~= 132.1 MB), lifetime-overlapped:
  //  WOT  [0, 2.1M)                     prep -> gemm_out
  //  segB QH|QL (33.55M)                qkv -> phi_q;  ATT reuses (attn -> gemm_out)
  //  segC KH|KL|VB|XH (67.1M)           splitx/qkv -> phik_kv; PHIQ reuses (phi_q -> attn)
  //  segD WTh|WTl (12.6M) + XL tail     prep/splitx -> qkv; KVP reuses (phik -> reduce)
  //  segE KVT (2.62M; under XL tail)    reduce -> attn (XL dead by then)
  const size_t PLANE = (size_t)8192 * 1024 * 2;  // 16,777,216
  char* ws = (char*)d_ws;
  unsigned short* WOT = (unsigned short*)(ws);
  char* segB = ws + 2097152;
  char* segC = segB + 2 * PLANE;
  char* segD = segC + 4 * PLANE;           // 67.1M segC
  char* segE = segD + 26214400;            // KVP size

  unsigned short* QH  = (unsigned short*)segB;
  unsigned short* QL  = (unsigned short*)(segB + PLANE);
  unsigned short* ATT = (unsigned short*)segB;

  unsigned short* KH  = (unsigned short*)segC;
  unsigned short* KL  = (unsigned short*)(segC + PLANE);
  unsigned short* VB  = (unsigned short*)(segC + 2 * PLANE);
  unsigned short* XH  = (unsigned short*)(segC + 3 * PLANE);
  unsigned short* PHIQ = (unsigned short*)segC;

  unsigned short* WTh = (unsigned short*)segD;
  unsigned short* WTl = (unsigned short*)(segD + 6291456);
  unsigned short* XL  = (unsigned short*)(segD + 12582912);  // 16.78M, spills 3.15M past segD into segE area
  float* KVP = (float*)segD;
  float* KVT = (float*)segE;

  k_split_x<<<dim3(4096), 256, 0, stream>>>(x, XH, XL);
  k_prep_w<<<dim3(16, 16, 4), 256, 0, stream>>>(wq, wk, wv, wo, WTh, WTl, WOT);
  k_gemm_qkv<<<dim3(24, 64), 256, 0, stream>>>(XH, XL, WTh, WTl, QH, QL, KH, KL, VB);
  k_phik_kv<<<dim3(8, 32), 256, 0, stream>>>(KH, KL, VB, om, KVP);
  k_kv_reduce<<<dim3(2560), 256, 0, stream>>>(KVP, KVT);
  k_phi_q<<<dim3(64, 32), 256, 0, stream>>>(QH, QL, om, PHIQ);
  k_attn<<<dim3(32, 32), 256, 0, stream>>>(PHIQ, KVT, ATT);
  k_gemm_out<<<dim3(8, 64), 256, 0, stream>>>(ATT, WOT, bo, out);
}

// Round 4
// 256.323 us; speedup vs baseline: 1.2890x; 1.1847x over previous
//
#include <hip/hip_runtime.h>

#define DEVI __device__ __forceinline__

using f32x4 = __attribute__((ext_vector_type(4))) float;
using fvec4 = __attribute__((ext_vector_type(4))) float;
using s16x4 = __attribute__((ext_vector_type(4))) short;
using s16x8 = __attribute__((ext_vector_type(8))) short;

DEVI unsigned short f2bf_rn(float f) {
  union { float f; unsigned u; } v; v.f = f;
  unsigned r = v.u + 0x7fffu + ((v.u >> 16) & 1u);
  return (unsigned short)(r >> 16);
}
DEVI float bf2f(unsigned short h) {
  union { unsigned u; float f; } v; v.u = ((unsigned)h) << 16;
  return v.f;
}
DEVI f32x4 mfma16(s16x8 a, s16x8 b, f32x4 c) {
  return __builtin_amdgcn_mfma_f32_16x16x32_bf16(a, b, c, 0, 0, 0);
}

// ---------------- split X f32 -> bf16 hi/lo (once) ----------------
__global__ __launch_bounds__(256) void k_split_x(
    const float* __restrict__ X,
    unsigned short* __restrict__ XH, unsigned short* __restrict__ XL)
{
  size_t i = ((size_t)blockIdx.x * 256 + threadIdx.x) * 8;
  fvec4 a = *(const fvec4*)&X[i];
  fvec4 b = *(const fvec4*)&X[i + 4];
  s16x8 hv, lv;
#pragma unroll
  for (int j = 0; j < 4; ++j) {
    unsigned short h = f2bf_rn(a[j]);
    hv[j] = (short)h; lv[j] = (short)f2bf_rn(a[j] - bf2f(h));
  }
#pragma unroll
  for (int j = 0; j < 4; ++j) {
    unsigned short h = f2bf_rn(b[j]);
    hv[4 + j] = (short)h; lv[4 + j] = (short)f2bf_rn(b[j] - bf2f(h));
  }
  *(s16x8*)&XH[i] = hv;
  *(s16x8*)&XL[i] = lv;
}

// ---------------- prep: transpose weights -> bf16 (single plane) ----------------
__global__ __launch_bounds__(256) void k_prep_w(
    const float* __restrict__ wq, const float* __restrict__ wk,
    const float* __restrict__ wv, const float* __restrict__ wo,
    unsigned short* __restrict__ WTh, unsigned short* __restrict__ WOT)
{
  __shared__ float tile[64][65];
  const int z = blockIdx.z;
  const float* src = (z == 0) ? wq : (z == 1) ? wk : (z == 2) ? wv : wo;
  const int k0 = blockIdx.x * 64;
  const int n0 = blockIdx.y * 64;
  const int t = threadIdx.x;
#pragma unroll
  for (int j = 0; j < 4; ++j) {
    int r = (t >> 4) + 16 * j;
    int c = (t & 15) * 4;
    fvec4 v = *(const fvec4*)&src[(size_t)(k0 + r) * 1024 + n0 + c];
#pragma unroll
    for (int i = 0; i < 4; ++i) tile[r][c + i] = v[i];
  }
  __syncthreads();
#pragma unroll
  for (int j = 0; j < 4; ++j) {
    int n = (t >> 4) + 16 * j;
    int kc = (t & 15) * 4;
    s16x4 hv;
#pragma unroll
    for (int i = 0; i < 4; ++i) hv[i] = (short)f2bf_rn(tile[kc + i][n]);
    if (z < 3) {
      *(s16x4*)&WTh[(size_t)(z * 1024 + n0 + n) * 1024 + k0 + kc] = hv;
    } else {
      *(s16x4*)&WOT[(size_t)(n0 + n) * 1024 + k0 + kc] = hv;
    }
  }
}

// ---------------- QKV GEMM: A split (2-pass), B single bf16 ----------------
__global__ __launch_bounds__(256) void k_gemm_qkv(
    const unsigned short* __restrict__ XH, const unsigned short* __restrict__ XL,
    const unsigned short* __restrict__ WTh,
    unsigned short* __restrict__ QH, unsigned short* __restrict__ QL,
    unsigned short* __restrict__ KH, unsigned short* __restrict__ KL,
    unsigned short* __restrict__ VB)
{
  __shared__ unsigned short AH[128][40], AL[128][40], BH[128][40];
  const int cb = blockIdx.x;  // 0..23
  const int rb = blockIdx.y;  // 0..63
  const int t = threadIdx.x;
  const int w = t >> 6, l = t & 63;
  const bool tp = (cb < 16);
  f32x4 acc[4][4];
#pragma unroll
  for (int a = 0; a < 4; ++a)
#pragma unroll
    for (int b = 0; b < 4; ++b) acc[a][b] = (f32x4)0.f;

  for (int ks = 0; ks < 32; ++ks) {
    const int k0 = ks * 32;
    {
      int r = t >> 1, c = (t & 1) * 16;
      size_t o = (size_t)(rb * 128 + r) * 1024 + k0 + c;
      *(s16x8*)&AH[r][c]     = *(const s16x8*)&XH[o];
      *(s16x8*)&AH[r][c + 8] = *(const s16x8*)&XH[o + 8];
      if (tp) {
        *(s16x8*)&AL[r][c]     = *(const s16x8*)&XL[o];
        *(s16x8*)&AL[r][c + 8] = *(const s16x8*)&XL[o + 8];
      }
      size_t ob = (size_t)(cb * 128 + r) * 1024 + k0 + c;
      *(s16x8*)&BH[r][c]     = *(const s16x8*)&WTh[ob];
      *(s16x8*)&BH[r][c + 8] = *(const s16x8*)&WTh[ob + 8];
    }
    __syncthreads();
    const int wm = (w & 1) * 64, wn = (w >> 1) * 64;
    const int lr = l & 15, ko = (l >> 4) * 8;
    s16x8 ah[4], al[4], bh[4];
#pragma unroll
    for (int f = 0; f < 4; ++f) {
      ah[f] = *(const s16x8*)&AH[wm + f * 16 + lr][ko];
      bh[f] = *(const s16x8*)&BH[wn + f * 16 + lr][ko];
    }
    if (tp) {
#pragma unroll
      for (int f = 0; f < 4; ++f) al[f] = *(const s16x8*)&AL[wm + f * 16 + lr][ko];
    }
#pragma unroll
    for (int fa = 0; fa < 4; ++fa)
#pragma unroll
      for (int fb = 0; fb < 4; ++fb) {
        acc[fa][fb] = mfma16(ah[fa], bh[fb], acc[fa][fb]);
        if (tp) acc[fa][fb] = mfma16(al[fa], bh[fb], acc[fa][fb]);
      }
    __syncthreads();
  }
  const int wm = (w & 1) * 64, wn = (w >> 1) * 64;
  const int lr = l & 15, lg = l >> 4;
#pragma unroll
  for (int fa = 0; fa < 4; ++fa)
#pragma unroll
    for (int r = 0; r < 4; ++r) {
      int row = rb * 128 + wm + fa * 16 + lg * 4 + r;
#pragma unroll
      for (int fb = 0; fb < 4; ++fb) {
        int col = cb * 128 + wn + fb * 16 + lr;
        float v = acc[fa][fb][r];
        unsigned short hs = f2bf_rn(v);
        if (cb < 8) {
          QH[(size_t)row * 1024 + col] = hs;
          QL[(size_t)row * 1024 + col] = f2bf_rn(v - bf2f(hs));
        } else if (cb < 16) {
          KH[(size_t)row * 1024 + col - 1024] = hs;
          KL[(size_t)row * 1024 + col - 1024] = f2bf_rn(v - bf2f(hs));
        } else {
          VB[(size_t)row * 1024 + col - 2048] = hs;
        }
      }
    }
}

// ---------------- fused phi_k + kv (512 threads, 8 waves, 2-pass proj) ------
__global__ __launch_bounds__(512, 1) void k_phik_kv(
    const unsigned short* __restrict__ KH, const unsigned short* __restrict__ KL,
    const unsigned short* __restrict__ VB,
    const float* __restrict__ omega, float* __restrict__ KVP)
{
  __shared__ unsigned short OH[256][72];
  __shared__ unsigned short KHs[64][72], KLs[64][72];
  __shared__ unsigned short PKT[256][72];
  __shared__ unsigned short AVT[80][72];
  __shared__ float norm_s[64];
  const int nc = blockIdx.x;  // 0..7
  const int bh = blockIdx.y;  // 0..31
  const int b = bh >> 4, h = bh & 15;
  const int t = threadIdx.x, w = t >> 6, l = t & 63;
  const int lr = l & 15, lg = l >> 4, ko8 = lg * 8;

  // stage omega bf16 (hi only) once
#pragma unroll
  for (int j = 0; j < 8; ++j) {
    int e = j * 512 + t;
    int m = e >> 4, c = (e & 15) * 4;
    fvec4 v = *(const fvec4*)&omega[m * 64 + c];
    s16x4 hv;
#pragma unroll
    for (int i = 0; i < 4; ++i) hv[i] = (short)f2bf_rn(v[i]);
    *(s16x4*)&OH[m][c] = hv;
  }
  for (int e = t; e < 16 * 64; e += 512) {
    int rr = e >> 6, cc = e & 63;
    AVT[64 + rr][cc] = (rr == 0) ? (unsigned short)0x3F80 : (unsigned short)0;
  }

  f32x4 acc2[5][2];
#pragma unroll
  for (int a = 0; a < 5; ++a)
#pragma unroll
    for (int bb = 0; bb < 2; ++bb) acc2[a][bb] = (f32x4)0.f;

  for (int st = 0; st < 8; ++st) {
    const int n0 = nc * 512 + st * 64;
    __syncthreads();
    // stage K hi/lo + row norms (8 threads per row)
    {
      int r = t >> 3, c8 = (t & 7) * 8;
      size_t o = (size_t)(b * 4096 + n0 + r) * 1024 + h * 64 + c8;
      s16x8 vh = *(const s16x8*)&KH[o];
      s16x8 vl = *(const s16x8*)&KL[o];
      *(s16x8*)&KHs[r][c8] = vh;
      *(s16x8*)&KLs[r][c8] = vl;
      float ss = 0.f;
#pragma unroll
      for (int i = 0; i < 8; ++i) {
        float q = bf2f((unsigned short)vh[i]) + bf2f((unsigned short)vl[i]);
        ss += q * q;
      }
      ss += __shfl_xor(ss, 1);
      ss += __shfl_xor(ss, 2);
      ss += __shfl_xor(ss, 4);
      if ((t & 7) == 0) norm_s[r] = 0.5f * ss;
    }
    // stage v^T
    {
      int n = t >> 3, dq = (t & 7) * 8;
      s16x8 v = *(const s16x8*)&VB[(size_t)(b * 4096 + n0 + n) * 1024 + h * 64 + dq];
#pragma unroll
      for (int i = 0; i < 8; ++i) AVT[dq + i][n] = (unsigned short)v[i];
    }
    __syncthreads();
    // proj MFMA 2-pass: wave w owns m-cols [w*32, w*32+32)
    f32x4 acc[4][2];
#pragma unroll
    for (int a = 0; a < 4; ++a)
#pragma unroll
      for (int bb = 0; bb < 2; ++bb) acc[a][bb] = (f32x4)0.f;
#pragma unroll
    for (int ksub = 0; ksub < 2; ++ksub) {
      int ko = ksub * 32 + ko8;
      s16x8 ah[4], al[4], bh[2];
#pragma unroll
      for (int f = 0; f < 4; ++f) {
        ah[f] = *(const s16x8*)&KHs[f * 16 + lr][ko];
        al[f] = *(const s16x8*)&KLs[f * 16 + lr][ko];
      }
#pragma unroll
      for (int f = 0; f < 2; ++f) bh[f] = *(const s16x8*)&OH[w * 32 + f * 16 + lr][ko];
#pragma unroll
      for (int fa = 0; fa < 4; ++fa)
#pragma unroll
        for (int fb = 0; fb < 2; ++fb) {
          acc[fa][fb] = mfma16(ah[fa], bh[fb], acc[fa][fb]);
          acc[fa][fb] = mfma16(al[fa], bh[fb], acc[fa][fb]);
        }
    }
    // exp -> phi_k transposed into PKT[m][n]
#pragma unroll
    for (int fa = 0; fa < 4; ++fa)
#pragma unroll
      for (int r = 0; r < 4; ++r) {
        int n = fa * 16 + lg * 4 + r;
        float nm = norm_s[n];
#pragma unroll
        for (int fb = 0; fb < 2; ++fb) {
          int m = w * 32 + fb * 16 + lr;
          float p = __expf(acc[fa][fb][r] - nm) * 0.0625f;
          PKT[m][n] = f2bf_rn(p);
        }
      }
    __syncthreads();
    // kv MFMA over n: wave w owns m-cols [w*32, ...)
#pragma unroll
    for (int ksub = 0; ksub < 2; ++ksub) {
      int ko = ksub * 32 + ko8;
      s16x8 fA[5], fB[2];
#pragma unroll
      for (int f = 0; f < 5; ++f) fA[f] = *(const s16x8*)&AVT[f * 16 + lr][ko];
#pragma unroll
      for (int f = 0; f < 2; ++f) fB[f] = *(const s16x8*)&PKT[w * 32 + f * 16 + lr][ko];
#pragma unroll
      for (int fa = 0; fa < 5; ++fa)
#pragma unroll
        for (int fb = 0; fb < 2; ++fb) acc2[fa][fb] = mfma16(fA[fa], fB[fb], acc2[fa][fb]);
    }
  }
#pragma unroll
  for (int fa = 0; fa < 5; ++fa)
#pragma unroll
    for (int r = 0; r < 4; ++r) {
      int dp = fa * 16 + lg * 4 + r;
#pragma unroll
      for (int fb = 0; fb < 2; ++fb) {
        int m = w * 32 + fb * 16 + lr;
        KVP[(size_t)((bh * 8 + nc) * 80 + dp) * 256 + m] = acc2[fa][fb][r];
      }
    }
}

__global__ __launch_bounds__(256) void k_kv_reduce(
    const float* __restrict__ KVP, float* __restrict__ KVT)
{
  int idx = blockIdx.x * 256 + threadIdx.x;
  if (idx >= 32 * 80 * 256) return;
  int bh = idx / (80 * 256);
  int rem = idx % (80 * 256);
  float s = 0.f;
#pragma unroll
  for (int nci = 0; nci < 8; ++nci) s += KVP[(size_t)(bh * 8 + nci) * 80 * 256 + rem];
  KVT[idx] = s;
}

// ---------------- phi_q (2-pass) ----------------
__global__ __launch_bounds__(256) void k_phi_q(
    const unsigned short* __restrict__ QH, const unsigned short* __restrict__ QL,
    const float* __restrict__ omega,
    unsigned short* __restrict__ PHIQ)
{
  __shared__ unsigned short AHs[64][72], ALs[64][72];
  __shared__ unsigned short OH[256][72];
  __shared__ float norm_s[64];
  const int nt = blockIdx.x;   // 0..63
  const int bh = blockIdx.y;   // 0..31
  const int t = threadIdx.x, w = t >> 6, l = t & 63;
  const int b = bh >> 4, h = bh & 15;
  {
    int r = t >> 2, cq = (t & 3) * 4;
    float ss = 0.f;
#pragma unroll
    for (int j = 0; j < 4; ++j) {
      int c = cq + 16 * j;
      size_t o = (size_t)(b * 4096 + nt * 64 + r) * 1024 + h * 64 + c;
      s16x4 vh = *(const s16x4*)&QH[o];
      s16x4 vl = *(const s16x4*)&QL[o];
      *(s16x4*)&AHs[r][c] = vh;
      *(s16x4*)&ALs[r][c] = vl;
#pragma unroll
      for (int i = 0; i < 4; ++i) {
        float q = bf2f((unsigned short)vh[i]) + bf2f((unsigned short)vl[i]);
        ss += q * q;
      }
    }
    ss += __shfl_xor(ss, 1);
    ss += __shfl_xor(ss, 2);
    if ((t & 3) == 0) norm_s[r] = 0.5f * ss;
  }
#pragma unroll
  for (int j = 0; j < 16; ++j) {
    int e = j * 256 + t;
    int m = e >> 4, c = (e & 15) * 4;
    fvec4 v = *(const fvec4*)&omega[m * 64 + c];
    s16x4 hv;
#pragma unroll
    for (int i = 0; i < 4; ++i) hv[i] = (short)f2bf_rn(v[i]);
    *(s16x4*)&OH[m][c] = hv;
  }
  __syncthreads();
  f32x4 acc[4][4];
#pragma unroll
  for (int a = 0; a < 4; ++a)
#pragma unroll
    for (int bb = 0; bb < 4; ++bb) acc[a][bb] = (f32x4)0.f;
  const int lr = l & 15, ko8 = (l >> 4) * 8;
#pragma unroll
  for (int ksub = 0; ksub < 2; ++ksub) {
    int ko = ksub * 32 + ko8;
    s16x8 ah[4], al[4], bh[4];
#pragma unroll
    for (int f = 0; f < 4; ++f) {
      ah[f] = *(const s16x8*)&AHs[f * 16 + lr][ko];
      al[f] = *(const s16x8*)&ALs[f * 16 + lr][ko];
      bh[f] = *(const s16x8*)&OH[w * 64 + f * 16 + lr][ko];
    }
#pragma unroll
    for (int fa = 0; fa < 4; ++fa)
#pragma unroll
      for (int fb = 0; fb < 4; ++fb) {
        acc[fa][fb] = mfma16(ah[fa], bh[fb], acc[fa][fb]);
        acc[fa][fb] = mfma16(al[fa], bh[fb], acc[fa][fb]);
      }
  }
  const int lg = l >> 4;
#pragma unroll
  for (int fa = 0; fa < 4; ++fa)
#pragma unroll
    for (int r = 0; r < 4; ++r) {
      int n = fa * 16 + lg * 4 + r;
      float nm = norm_s[n];
#pragma unroll
      for (int fb = 0; fb < 4; ++fb) {
        int m = w * 64 + fb * 16 + lr;
        float p = __expf(acc[fa][fb][r] - nm) * 0.0625f;
        PHIQ[(size_t)(bh * 4096 + nt * 64 + n) * 256 + m] = f2bf_rn(p);
      }
    }
}

// ---------------- attn: out = (phi_q @ kv) * z ----------------
__global__ __launch_bounds__(256) void k_attn(
    const unsigned short* __restrict__ PHIQ,
    const float* __restrict__ KVT,
    unsigned short* __restrict__ ATT)
{
  __shared__ unsigned short KVB[80][264];
  __shared__ unsigned short PH[128][40];
  const int ntile = blockIdx.x;  // 0..31
  const int bh = blockIdx.y;     // 0..31
  const int b = bh >> 4, h = bh & 15;
  const int t = threadIdx.x, w = t >> 6, l = t & 63;
#pragma unroll
  for (int j = 0; j < 20; ++j) {
    int e = (j * 256 + t) * 4;
    int dp = e >> 8, m = e & 255;
    fvec4 v = *(const fvec4*)&KVT[(size_t)bh * 80 * 256 + dp * 256 + m];
    s16x4 hv;
#pragma unroll
    for (int i = 0; i < 4; ++i) hv[i] = (short)f2bf_rn(v[i]);
    *(s16x4*)&KVB[dp][m] = hv;
  }
  __syncthreads();
  f32x4 acc[2][5];
#pragma unroll
  for (int a = 0; a < 2; ++a)
#pragma unroll
    for (int bb = 0; bb < 5; ++bb) acc[a][bb] = (f32x4)0.f;
  for (int ks = 0; ks < 8; ++ks) {
    const int m0 = ks * 32;
#pragma unroll
    for (int j = 0; j < 2; ++j) {
      int n = t >> 1, c = (t & 1) * 8 + j * 16;
      *(s16x8*)&PH[n][c] =
          *(const s16x8*)&PHIQ[(size_t)(bh * 4096 + ntile * 128 + n) * 256 + m0 + c];
    }
    __syncthreads();
    const int lr = l & 15, ko = (l >> 4) * 8;
    s16x8 fA[2], fB[5];
#pragma unroll
    for (int f = 0; f < 2; ++f) fA[f] = *(const s16x8*)&PH[w * 32 + f * 16 + lr][ko];
#pragma unroll
    for (int f = 0; f < 5; ++f) fB[f] = *(const s16x8*)&KVB[f * 16 + lr][m0 + ko];
#pragma unroll
    for (int fa = 0; fa < 2; ++fa)
#pragma unroll
      for (int fb = 0; fb < 5; ++fb) acc[fa][fb] = mfma16(fA[fa], fB[fb], acc[fa][fb]);
    __syncthreads();
  }
  const int lr = l & 15, lg = l >> 4;
#pragma unroll
  for (int fa = 0; fa < 2; ++fa)
#pragma unroll
    for (int r = 0; r < 4; ++r) {
      float den = __shfl(acc[fa][4][r], (l & 48));
      float z = 1.f / (den + 1e-6f);
      int n = ntile * 128 + w * 32 + fa * 16 + lg * 4 + r;
#pragma unroll
      for (int fb = 0; fb < 4; ++fb) {
        int col = h * 64 + fb * 16 + lr;
        ATT[(size_t)(b * 4096 + n) * 1024 + col] = f2bf_rn(acc[fa][fb][r] * z);
      }
    }
}

// ---------------- final GEMM: out = attn @ w_o + b_o ----------------
__global__ __launch_bounds__(256) void k_gemm_out(
    const unsigned short* __restrict__ ATT,
    const unsigned short* __restrict__ WOT,
    const float* __restrict__ b_o,
    float* __restrict__ OUT)
{
  __shared__ unsigned short As[128][40], Bs[128][40];
  const int cb = blockIdx.x;  // 0..7
  const int rb = blockIdx.y;  // 0..63
  const int t = threadIdx.x, w = t >> 6, l = t & 63;
  f32x4 acc[4][4];
#pragma unroll
  for (int a = 0; a < 4; ++a)
#pragma unroll
    for (int bb = 0; bb < 4; ++bb) acc[a][bb] = (f32x4)0.f;
  for (int ks = 0; ks < 32; ++ks) {
    const int k0 = ks * 32;
#pragma unroll
    for (int j = 0; j < 2; ++j) {
      int r = t >> 1, c = (t & 1) * 8 + j * 16;
      *(s16x8*)&As[r][c] = *(const s16x8*)&ATT[(size_t)(rb * 128 + r) * 1024 + k0 + c];
      *(s16x8*)&Bs[r][c] = *(const s16x8*)&WOT[(size_t)(cb * 128 + r) * 1024 + k0 + c];
    }
    __syncthreads();
    const int wm = (w & 1) * 64, wn = (w >> 1) * 64, lr = l & 15, ko = (l >> 4) * 8;
    s16x8 fA[4], fB[4];
#pragma unroll
    for (int f = 0; f < 4; ++f) {
      fA[f] = *(const s16x8*)&As[wm + f * 16 + lr][ko];
      fB[f] = *(const s16x8*)&Bs[wn + f * 16 + lr][ko];
    }
#pragma unroll
    for (int fa = 0; fa < 4; ++fa)
#pragma unroll
      for (int fb = 0; fb < 4; ++fb) acc[fa][fb] = mfma16(fA[fa], fB[fb], acc[fa][fb]);
    __syncthreads();
  }
  const int wm = (w & 1) * 64, wn = (w >> 1) * 64, lr = l & 15, lg = l >> 4;
#pragma unroll
  for (int fa = 0; fa < 4; ++fa)
#pragma unroll
    for (int r = 0; r < 4; ++r) {
      int row = rb * 128 + wm + fa * 16 + lg * 4 + r;
#pragma unroll
      for (int fb = 0; fb < 4; ++fb) {
        int col = cb * 128 + wn + fb * 16 + lr;
        OUT[(size_t)row * 1024 + col] = acc[fa][fb][r] + b_o[col];
      }
    }
}

extern "C" void kernel_launch(void* const* d_in, const int* in_sizes, int n_in,
                              void* d_out, int out_size, void* d_ws, size_t ws_size,
                              hipStream_t stream)
{
  const float* x  = (const float*)d_in[0];
  const float* wq = (const float*)d_in[1];
  const float* wk = (const float*)d_in[2];
  const float* wv = (const float*)d_in[3];
  const float* wo = (const float*)d_in[4];
  const float* bo = (const float*)d_in[5];
  const float* om = (const float*)d_in[6];
  float* out = (float*)d_out;

  // Workspace (~131.6 MB), lifetime-overlapped:
  //  WOT  2.1M                        prep -> gemm_out
  //  segB QH|QL 33.5M                 qkv -> phi_q;  ATT reuses (attn -> gemm_out)
  //  segC KH|KL|VB|XH 67.1M           splitx/qkv -> phik_kv; PHIQ reuses (phi_q -> attn)
  //  segD WTh 6.3M | XL 16.8M         prep/splitx -> qkv; KVP (26.2M) reuses
  //  segE KVT 2.62M                   reduce -> attn
  const size_t PLANE = (size_t)8192 * 1024 * 2;  // 16,777,216
  char* ws = (char*)d_ws;
  unsigned short* WOT = (unsigned short*)(ws);
  char* segB = ws + 2097152;
  char* segC = segB + 2 * PLANE;
  char* segD = segC + 4 * PLANE;
  char* segE = segD + 26214400;

  unsigned short* QH  = (unsigned short*)segB;
  unsigned short* QL  = (unsigned short*)(segB + PLANE);
  unsigned short* ATT = (unsigned short*)segB;

  unsigned short* KH  = (unsigned short*)segC;
  unsigned short* KL  = (unsigned short*)(segC + PLANE);
  unsigned short* VB  = (unsigned short*)(segC + 2 * PLANE);
  unsigned short* XH  = (unsigned short*)(segC + 3 * PLANE);
  unsigned short* PHIQ = (unsigned short*)segC;

  unsigned short* WTh = (unsigned short*)segD;
  unsigned short* XL  = (unsigned short*)(segD + 6291456);
  float* KVP = (float*)segD;
  float* KVT = (float*)segE;

  k_split_x<<<dim3(4096), 256, 0, stream>>>(x, XH, XL);
  k_prep_w<<<dim3(16, 16, 4), 256, 0, stream>>>(wq, wk, wv, wo, WTh, WOT);
  k_gemm_qkv<<<dim3(24, 64), 256, 0, stream>>>(XH, XL, WTh, QH, QL, KH, KL, VB);
  k_phik_kv<<<dim3(8, 32), 512, 0, stream>>>(KH, KL, VB, om, KVP);
  k_kv_reduce<<<dim3(2560), 256, 0, stream>>>(KVP, KVT);
  k_phi_q<<<dim3(64, 32), 256, 0, stream>>>(QH, QL, om, PHIQ);
  k_attn<<<dim3(32, 32), 256, 0, stream>>>(PHIQ, KVT, ATT);
  k_gemm_out<<<dim3(8, 64), 256, 0, stream>>>(ATT, WOT, bo, out);
}

// Round 5
// 233.326 us; speedup vs baseline: 1.4161x; 1.0986x over previous
//
#include <hip/hip_runtime.h>

#define DEVI __device__ __forceinline__

using f32x4 = __attribute__((ext_vector_type(4))) float;
using fvec4 = __attribute__((ext_vector_type(4))) float;
using s16x4 = __attribute__((ext_vector_type(4))) short;
using s16x8 = __attribute__((ext_vector_type(8))) short;

DEVI unsigned short f2bf_rn(float f) {
  union { float f; unsigned u; } v; v.f = f;
  unsigned r = v.u + 0x7fffu + ((v.u >> 16) & 1u);
  return (unsigned short)(r >> 16);
}
DEVI float bf2f(unsigned short h) {
  union { unsigned u; float f; } v; v.u = ((unsigned)h) << 16;
  return v.f;
}
DEVI f32x4 mfma16(s16x8 a, s16x8 b, f32x4 c) {
  return __builtin_amdgcn_mfma_f32_16x16x32_bf16(a, b, c, 0, 0, 0);
}
// async global->LDS, 16B per lane; lds base must be wave-uniform
DEVI void gld16(const void* g, void* lds) {
  __builtin_amdgcn_global_load_lds(
      (const __attribute__((address_space(1))) unsigned int*)g,
      (__attribute__((address_space(3))) unsigned int*)lds, 16, 0, 0);
}

// ---------------- split X f32 -> bf16 hi/lo (once) ----------------
__global__ __launch_bounds__(256) void k_split_x(
    const float* __restrict__ X,
    unsigned short* __restrict__ XH, unsigned short* __restrict__ XL)
{
  size_t i = ((size_t)blockIdx.x * 256 + threadIdx.x) * 8;
  fvec4 a = *(const fvec4*)&X[i];
  fvec4 b = *(const fvec4*)&X[i + 4];
  s16x8 hv, lv;
#pragma unroll
  for (int j = 0; j < 4; ++j) {
    unsigned short h = f2bf_rn(a[j]);
    hv[j] = (short)h; lv[j] = (short)f2bf_rn(a[j] - bf2f(h));
  }
#pragma unroll
  for (int j = 0; j < 4; ++j) {
    unsigned short h = f2bf_rn(b[j]);
    hv[4 + j] = (short)h; lv[4 + j] = (short)f2bf_rn(b[j] - bf2f(h));
  }
  *(s16x8*)&XH[i] = hv;
  *(s16x8*)&XL[i] = lv;
}

// ---------------- prep: transpose weights -> bf16 ----------------
__global__ __launch_bounds__(256) void k_prep_w(
    const float* __restrict__ wq, const float* __restrict__ wk,
    const float* __restrict__ wv, const float* __restrict__ wo,
    unsigned short* __restrict__ WTh, unsigned short* __restrict__ WOT)
{
  __shared__ float tile[64][65];
  const int z = blockIdx.z;
  const float* src = (z == 0) ? wq : (z == 1) ? wk : (z == 2) ? wv : wo;
  const int k0 = blockIdx.x * 64;
  const int n0 = blockIdx.y * 64;
  const int t = threadIdx.x;
#pragma unroll
  for (int j = 0; j < 4; ++j) {
    int r = (t >> 4) + 16 * j;
    int c = (t & 15) * 4;
    fvec4 v = *(const fvec4*)&src[(size_t)(k0 + r) * 1024 + n0 + c];
#pragma unroll
    for (int i = 0; i < 4; ++i) tile[r][c + i] = v[i];
  }
  __syncthreads();
#pragma unroll
  for (int j = 0; j < 4; ++j) {
    int n = (t >> 4) + 16 * j;
    int kc = (t & 15) * 4;
    s16x4 hv;
#pragma unroll
    for (int i = 0; i < 4; ++i) hv[i] = (short)f2bf_rn(tile[kc + i][n]);
    if (z < 3) {
      *(s16x4*)&WTh[(size_t)(z * 1024 + n0 + n) * 1024 + k0 + kc] = hv;
    } else {
      *(s16x4*)&WOT[(size_t)(n0 + n) * 1024 + k0 + kc] = hv;
    }
  }
}

// ---------------- QKV GEMM: global_load_lds staging, 2-pass A-split --------
__global__ __launch_bounds__(256) void k_gemm_qkv(
    const unsigned short* __restrict__ XH, const unsigned short* __restrict__ XL,
    const unsigned short* __restrict__ WTh,
    unsigned short* __restrict__ QH, unsigned short* __restrict__ QL,
    unsigned short* __restrict__ KH, unsigned short* __restrict__ KL,
    unsigned short* __restrict__ VB)
{
  __shared__ unsigned short AH[128 * 32], AL[128 * 32], BH[128 * 32];
  const int cb = blockIdx.x;  // 0..23
  const int rb = blockIdx.y;  // 0..63
  const int t = threadIdx.x;
  const int w = t >> 6, l = t & 63;
  const bool tp = (cb < 16);
  f32x4 acc[4][4];
#pragma unroll
  for (int a = 0; a < 4; ++a)
#pragma unroll
    for (int b = 0; b < 4; ++b) acc[a][b] = (f32x4)0.f;

  // per-lane global offsets (shorts); one gld16 covers 16 rows x 32 cols
  const int r0 = w * 32;              // wave's row block
  const int lrow = l >> 2;            // 0..15
  const int lcol = (l & 3) * 8;       // 0,8,16,24
  const size_t gA0 = (size_t)(rb * 128 + r0 + lrow) * 1024 + lcol;
  const size_t gA1 = gA0 + (size_t)16 * 1024;
  const size_t gB0 = (size_t)(cb * 128 + r0 + lrow) * 1024 + lcol;
  const size_t gB1 = gB0 + (size_t)16 * 1024;
  unsigned short* ldsA0 = &AH[r0 * 32];
  unsigned short* ldsA1 = &AH[(r0 + 16) * 32];
  unsigned short* ldsL0 = &AL[r0 * 32];
  unsigned short* ldsL1 = &AL[(r0 + 16) * 32];
  unsigned short* ldsB0 = &BH[r0 * 32];
  unsigned short* ldsB1 = &BH[(r0 + 16) * 32];

  const int wm = (w & 1) * 64, wn = (w >> 1) * 64;
  const int lr = l & 15, ko = (l >> 4) * 8;

  for (int ks = 0; ks < 32; ++ks) {
    const int k0 = ks * 32;
    gld16(&XH[gA0 + k0], ldsA0);
    gld16(&XH[gA1 + k0], ldsA1);
    if (tp) {
      gld16(&XL[gA0 + k0], ldsL0);
      gld16(&XL[gA1 + k0], ldsL1);
    }
    gld16(&WTh[gB0 + k0], ldsB0);
    gld16(&WTh[gB1 + k0], ldsB1);
    __syncthreads();
    s16x8 ah[4], al[4], bh[4];
#pragma unroll
    for (int f = 0; f < 4; ++f) {
      ah[f] = *(const s16x8*)&AH[(wm + f * 16 + lr) * 32 + ko];
      bh[f] = *(const s16x8*)&BH[(wn + f * 16 + lr) * 32 + ko];
    }
    if (tp) {
#pragma unroll
      for (int f = 0; f < 4; ++f) al[f] = *(const s16x8*)&AL[(wm + f * 16 + lr) * 32 + ko];
    }
#pragma unroll
    for (int fa = 0; fa < 4; ++fa)
#pragma unroll
      for (int fb = 0; fb < 4; ++fb) {
        acc[fa][fb] = mfma16(ah[fa], bh[fb], acc[fa][fb]);
        if (tp) acc[fa][fb] = mfma16(al[fa], bh[fb], acc[fa][fb]);
      }
    __syncthreads();
  }
  const int lg = l >> 4;
#pragma unroll
  for (int fa = 0; fa < 4; ++fa)
#pragma unroll
    for (int r = 0; r < 4; ++r) {
      int row = rb * 128 + wm + fa * 16 + lg * 4 + r;
#pragma unroll
      for (int fb = 0; fb < 4; ++fb) {
        int col = cb * 128 + wn + fb * 16 + lr;
        float v = acc[fa][fb][r];
        unsigned short hs = f2bf_rn(v);
        if (cb < 8) {
          QH[(size_t)row * 1024 + col] = hs;
          QL[(size_t)row * 1024 + col] = f2bf_rn(v - bf2f(hs));
        } else if (cb < 16) {
          KH[(size_t)row * 1024 + col - 1024] = hs;
          KL[(size_t)row * 1024 + col - 1024] = f2bf_rn(v - bf2f(hs));
        } else {
          VB[(size_t)row * 1024 + col - 2048] = hs;
        }
      }
    }
}

// ---------------- fused phi_k + kv (unchanged, bit-exact) ----------------
__global__ __launch_bounds__(512, 1) void k_phik_kv(
    const unsigned short* __restrict__ KH, const unsigned short* __restrict__ KL,
    const unsigned short* __restrict__ VB,
    const float* __restrict__ omega, float* __restrict__ KVP)
{
  __shared__ unsigned short OH[256][72];
  __shared__ unsigned short KHs[64][72], KLs[64][72];
  __shared__ unsigned short PKT[256][72];
  __shared__ unsigned short AVT[80][72];
  __shared__ float norm_s[64];
  const int nc = blockIdx.x;  // 0..7
  const int bh = blockIdx.y;  // 0..31
  const int b = bh >> 4, h = bh & 15;
  const int t = threadIdx.x, w = t >> 6, l = t & 63;
  const int lr = l & 15, lg = l >> 4, ko8 = lg * 8;

#pragma unroll
  for (int j = 0; j < 8; ++j) {
    int e = j * 512 + t;
    int m = e >> 4, c = (e & 15) * 4;
    fvec4 v = *(const fvec4*)&omega[m * 64 + c];
    s16x4 hv;
#pragma unroll
    for (int i = 0; i < 4; ++i) hv[i] = (short)f2bf_rn(v[i]);
    *(s16x4*)&OH[m][c] = hv;
  }
  for (int e = t; e < 16 * 64; e += 512) {
    int rr = e >> 6, cc = e & 63;
    AVT[64 + rr][cc] = (rr == 0) ? (unsigned short)0x3F80 : (unsigned short)0;
  }

  f32x4 acc2[5][2];
#pragma unroll
  for (int a = 0; a < 5; ++a)
#pragma unroll
    for (int bb = 0; bb < 2; ++bb) acc2[a][bb] = (f32x4)0.f;

  for (int st = 0; st < 8; ++st) {
    const int n0 = nc * 512 + st * 64;
    __syncthreads();
    {
      int r = t >> 3, c8 = (t & 7) * 8;
      size_t o = (size_t)(b * 4096 + n0 + r) * 1024 + h * 64 + c8;
      s16x8 vh = *(const s16x8*)&KH[o];
      s16x8 vl = *(const s16x8*)&KL[o];
      *(s16x8*)&KHs[r][c8] = vh;
      *(s16x8*)&KLs[r][c8] = vl;
      float ss = 0.f;
#pragma unroll
      for (int i = 0; i < 8; ++i) {
        float q = bf2f((unsigned short)vh[i]) + bf2f((unsigned short)vl[i]);
        ss += q * q;
      }
      ss += __shfl_xor(ss, 1);
      ss += __shfl_xor(ss, 2);
      ss += __shfl_xor(ss, 4);
      if ((t & 7) == 0) norm_s[r] = 0.5f * ss;
    }
    {
      int n = t >> 3, dq = (t & 7) * 8;
      s16x8 v = *(const s16x8*)&VB[(size_t)(b * 4096 + n0 + n) * 1024 + h * 64 + dq];
#pragma unroll
      for (int i = 0; i < 8; ++i) AVT[dq + i][n] = (unsigned short)v[i];
    }
    __syncthreads();
    f32x4 acc[4][2];
#pragma unroll
    for (int a = 0; a < 4; ++a)
#pragma unroll
      for (int bb = 0; bb < 2; ++bb) acc[a][bb] = (f32x4)0.f;
#pragma unroll
    for (int ksub = 0; ksub < 2; ++ksub) {
      int ko = ksub * 32 + ko8;
      s16x8 ah[4], al[4], bh[2];
#pragma unroll
      for (int f = 0; f < 4; ++f) {
        ah[f] = *(const s16x8*)&KHs[f * 16 + lr][ko];
        al[f] = *(const s16x8*)&KLs[f * 16 + lr][ko];
      }
#pragma unroll
      for (int f = 0; f < 2; ++f) bh[f] = *(const s16x8*)&OH[w * 32 + f * 16 + lr][ko];
#pragma unroll
      for (int fa = 0; fa < 4; ++fa)
#pragma unroll
        for (int fb = 0; fb < 2; ++fb) {
          acc[fa][fb] = mfma16(ah[fa], bh[fb], acc[fa][fb]);
          acc[fa][fb] = mfma16(al[fa], bh[fb], acc[fa][fb]);
        }
    }
#pragma unroll
    for (int fa = 0; fa < 4; ++fa)
#pragma unroll
      for (int r = 0; r < 4; ++r) {
        int n = fa * 16 + lg * 4 + r;
        float nm = norm_s[n];
#pragma unroll
        for (int fb = 0; fb < 2; ++fb) {
          int m = w * 32 + fb * 16 + lr;
          float p = __expf(acc[fa][fb][r] - nm) * 0.0625f;
          PKT[m][n] = f2bf_rn(p);
        }
      }
    __syncthreads();
#pragma unroll
    for (int ksub = 0; ksub < 2; ++ksub) {
      int ko = ksub * 32 + ko8;
      s16x8 fA[5], fB[2];
#pragma unroll
      for (int f = 0; f < 5; ++f) fA[f] = *(const s16x8*)&AVT[f * 16 + lr][ko];
#pragma unroll
      for (int f = 0; f < 2; ++f) fB[f] = *(const s16x8*)&PKT[w * 32 + f * 16 + lr][ko];
#pragma unroll
      for (int fa = 0; fa < 5; ++fa)
#pragma unroll
        for (int fb = 0; fb < 2; ++fb) acc2[fa][fb] = mfma16(fA[fa], fB[fb], acc2[fa][fb]);
    }
  }
#pragma unroll
  for (int fa = 0; fa < 5; ++fa)
#pragma unroll
    for (int r = 0; r < 4; ++r) {
      int dp = fa * 16 + lg * 4 + r;
#pragma unroll
      for (int fb = 0; fb < 2; ++fb) {
        int m = w * 32 + fb * 16 + lr;
        KVP[(size_t)((bh * 8 + nc) * 80 + dp) * 256 + m] = acc2[fa][fb][r];
      }
    }
}

__global__ __launch_bounds__(256) void k_kv_reduce(
    const float* __restrict__ KVP, float* __restrict__ KVT)
{
  int idx = blockIdx.x * 256 + threadIdx.x;
  if (idx >= 32 * 80 * 256) return;
  int bh = idx / (80 * 256);
  int rem = idx % (80 * 256);
  float s = 0.f;
#pragma unroll
  for (int nci = 0; nci < 8; ++nci) s += KVP[(size_t)(bh * 8 + nci) * 80 * 256 + rem];
  KVT[idx] = s;
}

// ---------------- fused phi_q + attn ----------------
// NOTE: ATT aliases QH's buffer; each (row,col) is read (QH/QL) then written
// (ATT) only by this same block, reads happen before writes -> no __restrict__.
__global__ __launch_bounds__(256) void k_phiq_attn(
    const unsigned short* QH, const unsigned short* QL,
    const float* __restrict__ omega, const float* __restrict__ KVT,
    unsigned short* ATT)
{
  __shared__ unsigned short QHs[64][72], QLs[64][72];
  __shared__ unsigned short OH[256][72];
  __shared__ unsigned short PQ[64][264];
  __shared__ unsigned short KVB[80][264];
  __shared__ float norm_s[64];
  const int nt = blockIdx.x;   // 0..63
  const int bh = blockIdx.y;   // 0..31
  const int t = threadIdx.x, w = t >> 6, l = t & 63;
  const int b = bh >> 4, h = bh & 15;
  const int lr = l & 15, lg = l >> 4, ko8 = lg * 8;

  // stage Q hi/lo + row norms (identical math to prior k_phi_q)
  {
    int r = t >> 2, cq = (t & 3) * 4;
    float ss = 0.f;
#pragma unroll
    for (int j = 0; j < 4; ++j) {
      int c = cq + 16 * j;
      size_t o = (size_t)(b * 4096 + nt * 64 + r) * 1024 + h * 64 + c;
      s16x4 vh = *(const s16x4*)&QH[o];
      s16x4 vl = *(const s16x4*)&QL[o];
      *(s16x4*)&QHs[r][c] = vh;
      *(s16x4*)&QLs[r][c] = vl;
#pragma unroll
      for (int i = 0; i < 4; ++i) {
        float q = bf2f((unsigned short)vh[i]) + bf2f((unsigned short)vl[i]);
        ss += q * q;
      }
    }
    ss += __shfl_xor(ss, 1);
    ss += __shfl_xor(ss, 2);
    if ((t & 3) == 0) norm_s[r] = 0.5f * ss;
  }
  // stage omega bf16
#pragma unroll
  for (int j = 0; j < 16; ++j) {
    int e = j * 256 + t;
    int m = e >> 4, c = (e & 15) * 4;
    fvec4 v = *(const fvec4*)&omega[m * 64 + c];
    s16x4 hv;
#pragma unroll
    for (int i = 0; i < 4; ++i) hv[i] = (short)f2bf_rn(v[i]);
    *(s16x4*)&OH[m][c] = hv;
  }
  // stage kv^T -> bf16 (identical math to prior k_attn)
#pragma unroll
  for (int j = 0; j < 20; ++j) {
    int e = (j * 256 + t) * 4;
    int dp = e >> 8, m = e & 255;
    fvec4 v = *(const fvec4*)&KVT[(size_t)bh * 80 * 256 + dp * 256 + m];
    s16x4 hv;
#pragma unroll
    for (int i = 0; i < 4; ++i) hv[i] = (short)f2bf_rn(v[i]);
    *(s16x4*)&KVB[dp][m] = hv;
  }
  __syncthreads();
  // proj 2-pass MFMA
  f32x4 acc[4][4];
#pragma unroll
  for (int a = 0; a < 4; ++a)
#pragma unroll
    for (int bb = 0; bb < 4; ++bb) acc[a][bb] = (f32x4)0.f;
#pragma unroll
  for (int ksub = 0; ksub < 2; ++ksub) {
    int ko = ksub * 32 + ko8;
    s16x8 ah[4], al[4], bh[4];
#pragma unroll
    for (int f = 0; f < 4; ++f) {
      ah[f] = *(const s16x8*)&QHs[f * 16 + lr][ko];
      al[f] = *(const s16x8*)&QLs[f * 16 + lr][ko];
      bh[f] = *(const s16x8*)&OH[w * 64 + f * 16 + lr][ko];
    }
#pragma unroll
    for (int fa = 0; fa < 4; ++fa)
#pragma unroll
      for (int fb = 0; fb < 4; ++fb) {
        acc[fa][fb] = mfma16(ah[fa], bh[fb], acc[fa][fb]);
        acc[fa][fb] = mfma16(al[fa], bh[fb], acc[fa][fb]);
      }
  }
  // exp -> phi_q into PQ[n][m] (bf16, same rounding as before)
#pragma unroll
  for (int fa = 0; fa < 4; ++fa)
#pragma unroll
    for (int r = 0; r < 4; ++r) {
      int n = fa * 16 + lg * 4 + r;
      float nm = norm_s[n];
#pragma unroll
      for (int fb = 0; fb < 4; ++fb) {
        int m = w * 64 + fb * 16 + lr;
        float p = __expf(acc[fa][fb][r] - nm) * 0.0625f;
        PQ[n][m] = f2bf_rn(p);
      }
    }
  __syncthreads();
  // attn MFMA: wave w owns rows [w*16, w*16+16)
  f32x4 acc2[5];
#pragma unroll
  for (int bb = 0; bb < 5; ++bb) acc2[bb] = (f32x4)0.f;
  for (int ks = 0; ks < 8; ++ks) {
    const int m0 = ks * 32;
    s16x8 fA = *(const s16x8*)&PQ[w * 16 + lr][m0 + ko8];
    s16x8 fB[5];
#pragma unroll
    for (int f = 0; f < 5; ++f) fB[f] = *(const s16x8*)&KVB[f * 16 + lr][m0 + ko8];
#pragma unroll
    for (int fb = 0; fb < 5; ++fb) acc2[fb] = mfma16(fA, fB[fb], acc2[fb]);
  }
#pragma unroll
  for (int r = 0; r < 4; ++r) {
    float den = __shfl(acc2[4][r], (l & 48));
    float z = 1.f / (den + 1e-6f);
    int n = nt * 64 + w * 16 + lg * 4 + r;
#pragma unroll
    for (int fb = 0; fb < 4; ++fb) {
      int col = h * 64 + fb * 16 + lr;
      ATT[(size_t)(b * 4096 + n) * 1024 + col] = f2bf_rn(acc2[fb][r] * z);
    }
  }
}

// ---------------- final GEMM with global_load_lds ----------------
__global__ __launch_bounds__(256) void k_gemm_out(
    const unsigned short* __restrict__ ATT,
    const unsigned short* __restrict__ WOT,
    const float* __restrict__ b_o,
    float* __restrict__ OUT)
{
  __shared__ unsigned short As[128 * 32], Bs[128 * 32];
  const int cb = blockIdx.x;  // 0..7
  const int rb = blockIdx.y;  // 0..63
  const int t = threadIdx.x, w = t >> 6, l = t & 63;
  f32x4 acc[4][4];
#pragma unroll
  for (int a = 0; a < 4; ++a)
#pragma unroll
    for (int bb = 0; bb < 4; ++bb) acc[a][bb] = (f32x4)0.f;

  const int r0 = w * 32;
  const int lrow = l >> 2;
  const int lcol = (l & 3) * 8;
  const size_t gA0 = (size_t)(rb * 128 + r0 + lrow) * 1024 + lcol;
  const size_t gA1 = gA0 + (size_t)16 * 1024;
  const size_t gB0 = (size_t)(cb * 128 + r0 + lrow) * 1024 + lcol;
  const size_t gB1 = gB0 + (size_t)16 * 1024;
  unsigned short* ldsA0 = &As[r0 * 32];
  unsigned short* ldsA1 = &As[(r0 + 16) * 32];
  unsigned short* ldsB0 = &Bs[r0 * 32];
  unsigned short* ldsB1 = &Bs[(r0 + 16) * 32];

  const int wm = (w & 1) * 64, wn = (w >> 1) * 64;
  const int lr = l & 15, ko = (l >> 4) * 8;

  for (int ks = 0; ks < 32; ++ks) {
    const int k0 = ks * 32;
    gld16(&ATT[gA0 + k0], ldsA0);
    gld16(&ATT[gA1 + k0], ldsA1);
    gld16(&WOT[gB0 + k0], ldsB0);
    gld16(&WOT[gB1 + k0], ldsB1);
    __syncthreads();
    s16x8 fA[4], fB[4];
#pragma unroll
    for (int f = 0; f < 4; ++f) {
      fA[f] = *(const s16x8*)&As[(wm + f * 16 + lr) * 32 + ko];
      fB[f] = *(const s16x8*)&Bs[(wn + f * 16 + lr) * 32 + ko];
    }
#pragma unroll
    for (int fa = 0; fa < 4; ++fa)
#pragma unroll
      for (int fb = 0; fb < 4; ++fb) acc[fa][fb] = mfma16(fA[fa], fB[fb], acc[fa][fb]);
    __syncthreads();
  }
  const int lg = l >> 4;
#pragma unroll
  for (int fa = 0; fa < 4; ++fa)
#pragma unroll
    for (int r = 0; r < 4; ++r) {
      int row = rb * 128 + wm + fa * 16 + lg * 4 + r;
#pragma unroll
      for (int fb = 0; fb < 4; ++fb) {
        int col = cb * 128 + wn + fb * 16 + lr;
        OUT[(size_t)row * 1024 + col] = acc[fa][fb][r] + b_o[col];
      }
    }
}

extern "C" void kernel_launch(void* const* d_in, const int* in_sizes, int n_in,
                              void* d_out, int out_size, void* d_ws, size_t ws_size,
                              hipStream_t stream)
{
  const float* x  = (const float*)d_in[0];
  const float* wq = (const float*)d_in[1];
  const float* wk = (const float*)d_in[2];
  const float* wv = (const float*)d_in[3];
  const float* wo = (const float*)d_in[4];
  const float* bo = (const float*)d_in[5];
  const float* om = (const float*)d_in[6];
  float* out = (float*)d_out;

  // Workspace (~131.6 MB), lifetime-overlapped (same proven layout as R4):
  //  WOT  2.1M                     prep -> gemm_out
  //  segB QH|QL 33.5M              qkv -> phiq_attn; ATT reuses QH plane
  //  segC KH|KL|VB|XH 67.1M        splitx/qkv -> phik_kv
  //  segD WTh 6.3M | XL 16.8M      prep/splitx -> qkv; KVP (26.2M) reuses
  //  segE KVT 2.62M                reduce -> phiq_attn
  const size_t PLANE = (size_t)8192 * 1024 * 2;  // 16,777,216
  char* ws = (char*)d_ws;
  unsigned short* WOT = (unsigned short*)(ws);
  char* segB = ws + 2097152;
  char* segC = segB + 2 * PLANE;
  char* segD = segC + 4 * PLANE;
  char* segE = segD + 26214400;

  unsigned short* QH  = (unsigned short*)segB;
  unsigned short* QL  = (unsigned short*)(segB + PLANE);
  unsigned short* ATT = (unsigned short*)segB;   // aliases QH (safe, see kernel)

  unsigned short* KH  = (unsigned short*)segC;
  unsigned short* KL  = (unsigned short*)(segC + PLANE);
  unsigned short* VB  = (unsigned short*)(segC + 2 * PLANE);
  unsigned short* XH  = (unsigned short*)(segC + 3 * PLANE);

  unsigned short* WTh = (unsigned short*)segD;
  unsigned short* XL  = (unsigned short*)(segD + 6291456);
  float* KVP = (float*)segD;
  float* KVT = (float*)segE;

  k_split_x<<<dim3(4096), 256, 0, stream>>>(x, XH, XL);
  k_prep_w<<<dim3(16, 16, 4), 256, 0, stream>>>(wq, wk, wv, wo, WTh, WOT);
  k_gemm_qkv<<<dim3(24, 64), 256, 0, stream>>>(XH, XL, WTh, QH, QL, KH, KL, VB);
  k_phik_kv<<<dim3(8, 32), 512, 0, stream>>>(KH, KL, VB, om, KVP);
  k_kv_reduce<<<dim3(2560), 256, 0, stream>>>(KVP, KVT);
  k_phiq_attn<<<dim3(64, 32), 256, 0, stream>>>(QH, QL, om, KVT, ATT);
  k_gemm_out<<<dim3(8, 64), 256, 0, stream>>>(ATT, WOT, bo, out);
}